// Round 1
// baseline (326.215 us; speedup 1.0000x reference)
//
#include <hip/hip_runtime.h>
#include <math.h>

#define TAUF  1.0e-4f
#define LNEPS 1.0e-5f

// ---------------- workspace layout (float offsets) ----------------
// Zr (B*16*1536) is dead after the attn GEMM; h (B*16*1024) aliases it.
static const unsigned ZR_OFF  = 0u;         // 6,291,456 floats (h alias needs 4,194,304)
static const unsigned RSA_OFF = 6291456u;   // 256*48
static const unsigned Q_OFF   = 6303744u;   // 1536*256
static const unsigned CE_OFF  = 6696960u;   // 3*256
static const unsigned B0_OFF  = 6697728u;   // 256
static const unsigned C0_OFF  = 6697984u;   // 256
static const unsigned C1_OFF  = 6698240u;   // 256
static const unsigned U_OFF   = 6698496u;   // 16*560
static const unsigned SG_OFF  = 6707456u;   // 560
static const unsigned R1_OFF  = 6708016u;   // 16
static const unsigned R2_OFF  = 6708032u;   // 16
static const unsigned X2_OFF  = 6708048u;   // 256*16*256
static const unsigned X2N_OFF = 7756624u;   // 256*16*256
static const unsigned WS_FLOATS = 8805200u; // ~35.2 MB

// ---------------- constants of the complex: C0, C1, U, sigma, r1, r2 ----------------
__launch_bounds__(256)
__global__ void p0_const_k(const float* __restrict__ B1g, const float* __restrict__ absB1,
                           const float* __restrict__ B2g,
                           float* __restrict__ C0, float* __restrict__ C1,
                           float* __restrict__ U, float* __restrict__ sigma,
                           float* __restrict__ r1, float* __restrict__ r2)
{
    int tid = threadIdx.x;
    if (blockIdx.x == 0) {
        int p = tid >> 4, q = tid & 15;
        float c0 = 0.f, c1 = 0.f;
        for (int e = 0; e < 120; ++e) {
            float ap = absB1[p*120+e];
            c0 += ap * B1g[q*120+e];
            c1 += ap * absB1[q*120+e];
        }
        C0[tid] = c0; C1[tid] = c1;
        if (tid < 16) {
            float a = 0.f, b = 0.f;
            for (int e = 0; e < 120; ++e) { a += B1g[tid*120+e]; b += absB1[tid*120+e]; }
            r1[tid] = a; r2[tid] = b;
        }
        for (int t = tid; t < 560; t += 256) {
            float s = 0.f;
            for (int e = 0; e < 120; ++e) s += B2g[e*560+t];
            sigma[t] = s;
        }
    } else {
        int idx = (blockIdx.x - 1) * 256 + tid;       // 0..8959 over 35 blocks
        int p = idx / 560, t = idx % 560;
        float u = 0.f;
        for (int e = 0; e < 120; ++e) u += absB1[p*120+e] * B2g[e*560+t];
        U[idx] = u;
    }
}

// ---------------- fold wv0/wein into out_w:  Q[blk*256+c', o] ----------------
__launch_bounds__(256)
__global__ void p1_q_k(const float* __restrict__ wv0_w, const float* __restrict__ wein_w,
                       const float* __restrict__ out_w, float* __restrict__ Q)
{
    int r0  = blockIdx.x * 4;            // 4 rows per block, grid = 384
    int blk = r0 >> 8;
    int s   = (blk < 3) ? blk : blk - 3;
    const float* Wsel = (blk < 3) ? wv0_w : wein_w;
    int cp0 = r0 & 255;
    int o = threadIdx.x;
    float a0 = 0.f, a1 = 0.f, a2 = 0.f, a3 = 0.f;
    for (int c = 0; c < 256; ++c) {
        float ow = out_w[(size_t)(blk*256 + c)*256 + o];
        a0 += Wsel[(size_t)(cp0+0)*768 + s*256 + c] * ow;
        a1 += Wsel[(size_t)(cp0+1)*768 + s*256 + c] * ow;
        a2 += Wsel[(size_t)(cp0+2)*768 + s*256 + c] * ow;
        a3 += Wsel[(size_t)(cp0+3)*768 + s*256 + c] * ow;
    }
    Q[(size_t)(r0+0)*256 + o] = a0;
    Q[(size_t)(r0+1)*256 + o] = a1;
    Q[(size_t)(r0+2)*256 + o] = a2;
    Q[(size_t)(r0+3)*256 + o] = a3;
}

// ---------------- bias folding: bias0 = out_b + TAU*(wv0_b @ out_w_node); ce_s = wein_b_s @ out_w_edge_s ----------------
__launch_bounds__(256)
__global__ void p2_misc_k(const float* __restrict__ wv0_b, const float* __restrict__ wein_b,
                          const float* __restrict__ out_w, const float* __restrict__ out_b,
                          float* __restrict__ ce, float* __restrict__ bias0)
{
    int o = threadIdx.x;
    float acc = 0.f;
    for (int r = 0; r < 768; ++r) acc += wv0_b[r] * out_w[(size_t)r*256 + o];
    bias0[o] = out_b[o] + TAUF * acc;
    for (int s = 0; s < 3; ++s) {
        float a2 = 0.f;
        for (int c = 0; c < 256; ++c)
            a2 += wein_b[s*256 + c] * out_w[(size_t)(768 + s*256 + c)*256 + o];
        ce[s*256 + o] = a2;
    }
}

// ---------------- per-batch: LN1, P, W1, W2, six 16x16 operators, Z = O @ xn ----------------
__launch_bounds__(256)
__global__ void k1_build(const float* __restrict__ x, const float* __restrict__ mask,
                         const float* __restrict__ B1g,
                         const int* __restrict__ e_i, const int* __restrict__ e_j,
                         const int* __restrict__ t_ij, const int* __restrict__ t_jk,
                         const int* __restrict__ t_ik,
                         const float* __restrict__ geom_w, const float* __restrict__ geom_b,
                         const float* __restrict__ log_sc,
                         const float* __restrict__ n1_g, const float* __restrict__ n1_b,
                         const float* __restrict__ C0, const float* __restrict__ C1,
                         const float* __restrict__ U, const float* __restrict__ sigma,
                         const float* __restrict__ r1, const float* __restrict__ r2,
                         float* __restrict__ Zr, float* __restrict__ rsA)
{
    __shared__ float sxn[16][256];
    __shared__ float sP[16][16];
    __shared__ float sW1[3][120];
    __shared__ float sW2[3][560];
    __shared__ float sB1[16*121];   // odd-ish stride 121 -> conflict-free column reads
    __shared__ float sU[16*561];    // stride 561
    __shared__ float sO[6][16][16];
    __shared__ float sMask[16];

    int bb = blockIdx.x, tid = threadIdx.x;
    int r = tid >> 4, g = tid & 15;

    // ---- LayerNorm 1 (16 threads per row, 16 elems each) ----
    {
        const float* row = x + ((size_t)bb*16 + r)*256;
        float v[16]; float sum = 0.f, ss = 0.f;
        #pragma unroll
        for (int m = 0; m < 16; ++m) { float t = row[g*16 + m]; v[m] = t; sum += t; ss += t*t; }
        #pragma unroll
        for (int o = 8; o; o >>= 1) { sum += __shfl_xor(sum, o); ss += __shfl_xor(ss, o); }
        float mean = sum * (1.f/256.f);
        float rstd = rsqrtf(ss*(1.f/256.f) - mean*mean + LNEPS);
        #pragma unroll
        for (int m = 0; m < 16; ++m) {
            int c = g*16 + m;
            sxn[r][c] = (v[m]-mean)*rstd*n1_g[c] + n1_b[c];
        }
        if (tid < 16) sMask[tid] = mask[bb*16 + tid];
    }
    // stage B1 and U into LDS (padded strides)
    for (int i = tid; i < 16*120; i += 256) sB1[(i/120)*121 + (i%120)] = B1g[i];
    for (int i = tid; i < 16*560; i += 256) sU[(i/560)*561 + (i%560)] = U[i];
    __syncthreads();

    // ---- P = xn @ geom_w + geom_b  (16x16) ----
    {
        float acc = geom_b[g];
        for (int c = 0; c < 256; ++c) acc += sxn[r][c] * geom_w[c*16 + g];
        sP[r][g] = acc;
    }
    __syncthreads();

    // ---- W1 (3 x 120) ----
    float denom[3];
    #pragma unroll
    for (int s = 0; s < 3; ++s) { float sc = expf(log_sc[s]); denom[s] = 2.f*sc*sc + 1e-8f; }
    if (tid < 120) {
        int e = tid, i0 = e_i[e], j0 = e_j[e];
        float d2 = 0.f;
        #pragma unroll
        for (int m = 0; m < 16; ++m) { float dd = sP[i0][m] - sP[j0][m]; d2 += dd*dd; }
        float mm = sMask[i0]*sMask[j0];
        d2 *= mm*mm;
        #pragma unroll
        for (int s = 0; s < 3; ++s) sW1[s][e] = expf(-d2/denom[s]) * mm;
    }
    __syncthreads();

    // ---- W2 (3 x 560) ----
    for (int t = tid; t < 560; t += 256) {
        int a = t_ij[t], b2 = t_jk[t], c2 = t_ik[t];
        #pragma unroll
        for (int s = 0; s < 3; ++s) sW2[s][t] = sW1[s][a]*sW1[s][b2]*sW1[s][c2];
    }
    __syncthreads();

    // ---- operators: thread -> (k,l) entry ----
    int k = tid >> 4, l = tid & 15;
    // node: L0_s = B1 diag(W1_s) B1^T + TAU I
    #pragma unroll
    for (int s = 0; s < 3; ++s) {
        float acc = 0.f;
        for (int e = 0; e < 120; ++e) acc += sW1[s][e]*sB1[k*121+e]*sB1[l*121+e];
        sO[s][k][l] = acc + ((k == l) ? TAUF : 0.f);
    }
    // edge: H_s = C0 diag(mask) C0^T + U diag(W2_s) U^T + TAU C1
    float hbase;
    {
        float hd = 0.f;
        #pragma unroll
        for (int p = 0; p < 16; ++p) hd += C0[k*16+p]*sMask[p]*C0[l*16+p];
        hbase = hd + TAUF*C1[k*16+l];
    }
    #pragma unroll
    for (int s = 0; s < 3; ++s) {
        float acc = 0.f;
        for (int t = 0; t < 560; ++t) acc += sW2[s][t]*sU[k*561+t]*sU[l*561+t];
        sO[3+s][k][l] = hbase + acc;
    }
    // rowsumA[b,s,k] = C0@(mask*r1) + U@(W2_s*sigma) + TAU*r2
    if (tid < 48) {
        int s = tid / 16, kk = tid & 15;
        float acc = TAUF * r2[kk];
        #pragma unroll
        for (int p = 0; p < 16; ++p) acc += C0[kk*16+p]*sMask[p]*r1[p];
        for (int t = 0; t < 560; ++t) acc += sU[kk*561+t]*sW2[s][t]*sigma[t];
        rsA[bb*48 + s*16 + kk] = acc;
    }
    __syncthreads();

    // ---- Zr[b, k, blk*256+c] = (O_blk @ xn)[k, c] ----
    #pragma unroll
    for (int blk = 0; blk < 6; ++blk) {
        #pragma unroll
        for (int kk = 0; kk < 16; ++kk) {
            float acc = 0.f;
            #pragma unroll
            for (int l2 = 0; l2 < 16; ++l2) acc += sO[blk][kk][l2]*sxn[l2][tid];
            Zr[((size_t)bb*16 + kk)*1536 + blk*256 + tid] = acc;
        }
    }
}

// ---------------- row LayerNorm (for x2 -> x2n) ----------------
__launch_bounds__(256)
__global__ void ln_rows(const float* __restrict__ in, const float* __restrict__ gamma,
                        const float* __restrict__ beta, float* __restrict__ out)
{
    int bb = blockIdx.x, tid = threadIdx.x;
    int r = tid >> 4, g = tid & 15;
    const float* row = in + ((size_t)bb*16 + r)*256;
    float v[16]; float sum = 0.f, ss = 0.f;
    #pragma unroll
    for (int m = 0; m < 16; ++m) { float t = row[g*16 + m]; v[m] = t; sum += t; ss += t*t; }
    #pragma unroll
    for (int o = 8; o; o >>= 1) { sum += __shfl_xor(sum, o); ss += __shfl_xor(ss, o); }
    float mean = sum * (1.f/256.f);
    float rstd = rsqrtf(ss*(1.f/256.f) - mean*mean + LNEPS);
    float* orow = out + ((size_t)bb*16 + r)*256;
    #pragma unroll
    for (int m = 0; m < 16; ++m) {
        int c = g*16 + m;
        orow[c] = (v[m]-mean)*rstd*gamma[c] + beta[c];
    }
}

// ---------------- generic 64x64 f32 GEMM tile, 4x4 per thread ----------------
// EPI 0: attn epilogue (bias0 + rsA*ce + residual x) -> x2
// EPI 1: +bias, exact gelu -> h
// EPI 2: +bias + residual x2 -> out
template<int EPI>
__launch_bounds__(256)
__global__ void gemm_tile(const float* __restrict__ A, int lda,
                          const float* __restrict__ Bw, int ldb,
                          int nkt,
                          const float* __restrict__ p0,
                          const float* __restrict__ p1,
                          const float* __restrict__ p2,
                          const float* __restrict__ p3,
                          float* __restrict__ Cout, int ldc)
{
    __shared__ float Ast[16][68];  // [kk][row]
    __shared__ float Bs[16][68];   // [kk][col]
    int row0 = blockIdx.y * 64, col0 = blockIdx.x * 64;
    int tid = threadIdx.x;
    int tx = tid & 15, ty = tid >> 4;
    int ar = tid >> 2, ac = (tid & 3) << 2;       // A loader: row, k-col
    int bk = tid >> 4, bc = (tid & 15) << 2;      // B loader: k-row, col
    float acc[4][4] = {};

    for (int kt = 0; kt < nkt; ++kt) {
        int k0 = kt * 16;
        float4 av = *(const float4*)(A  + (size_t)(row0 + ar)*lda + k0 + ac);
        float4 bv = *(const float4*)(Bw + (size_t)(k0 + bk)*ldb + col0 + bc);
        __syncthreads();
        Ast[ac+0][ar] = av.x; Ast[ac+1][ar] = av.y; Ast[ac+2][ar] = av.z; Ast[ac+3][ar] = av.w;
        *(float4*)(&Bs[bk][bc]) = bv;
        __syncthreads();
        #pragma unroll
        for (int kk = 0; kk < 16; ++kk) {
            float4 a = *(const float4*)(&Ast[kk][ty*4]);
            float4 b = *(const float4*)(&Bs[kk][tx*4]);
            acc[0][0] += a.x*b.x; acc[0][1] += a.x*b.y; acc[0][2] += a.x*b.z; acc[0][3] += a.x*b.w;
            acc[1][0] += a.y*b.x; acc[1][1] += a.y*b.y; acc[1][2] += a.y*b.z; acc[1][3] += a.y*b.w;
            acc[2][0] += a.z*b.x; acc[2][1] += a.z*b.y; acc[2][2] += a.z*b.z; acc[2][3] += a.z*b.w;
            acc[3][0] += a.w*b.x; acc[3][1] += a.w*b.y; acc[3][2] += a.w*b.z; acc[3][3] += a.w*b.w;
        }
    }
    #pragma unroll
    for (int i = 0; i < 4; ++i) {
        int rowg = row0 + ty*4 + i;
        #pragma unroll
        for (int j = 0; j < 4; ++j) {
            int colg = col0 + tx*4 + j;
            float v = acc[i][j];
            if (EPI == 0) {
                int b = rowg >> 4, kk = rowg & 15;
                v += p0[colg]
                   + p1[b*48 +      kk] * p2[colg]
                   + p1[b*48 + 16 + kk] * p2[256 + colg]
                   + p1[b*48 + 32 + kk] * p2[512 + colg]
                   + p3[(size_t)rowg*256 + colg];
            } else if (EPI == 1) {
                v += p0[colg];
                v = 0.5f * v * (1.f + erff(v * 0.70710678118654752f));
            } else {
                v += p0[colg] + p1[(size_t)rowg*256 + colg];
            }
            Cout[(size_t)rowg*ldc + colg] = v;
        }
    }
}

extern "C" void kernel_launch(void* const* d_in, const int* in_sizes, int n_in,
                              void* d_out, int out_size, void* d_ws, size_t ws_size,
                              hipStream_t stream)
{
    (void)in_sizes; (void)n_in; (void)out_size;
    const float* x      = (const float*)d_in[0];
    const float* mask   = (const float*)d_in[1];
    const float* B1g    = (const float*)d_in[2];
    const float* B2g    = (const float*)d_in[3];
    const float* absB1  = (const float*)d_in[4];
    const int*   e_i    = (const int*)d_in[5];
    const int*   e_j    = (const int*)d_in[6];
    const int*   t_ij   = (const int*)d_in[7];
    const int*   t_jk   = (const int*)d_in[8];
    const int*   t_ik   = (const int*)d_in[9];
    const float* geom_w = (const float*)d_in[10];
    const float* geom_b = (const float*)d_in[11];
    const float* log_sc = (const float*)d_in[12];
    const float* wv0_w  = (const float*)d_in[13];
    const float* wv0_b  = (const float*)d_in[14];
    const float* wein_w = (const float*)d_in[15];
    const float* wein_b = (const float*)d_in[16];
    const float* out_w  = (const float*)d_in[17];
    const float* out_b  = (const float*)d_in[18];
    const float* n1_g   = (const float*)d_in[19];
    const float* n1_b   = (const float*)d_in[20];
    const float* n2_g   = (const float*)d_in[21];
    const float* n2_b   = (const float*)d_in[22];
    const float* ffn1_w = (const float*)d_in[23];
    const float* ffn1_b = (const float*)d_in[24];
    const float* ffn2_w = (const float*)d_in[25];
    const float* ffn2_b = (const float*)d_in[26];

    float* out = (float*)d_out;
    float* ws  = (float*)d_ws;
    if (ws_size < (size_t)WS_FLOATS * sizeof(float)) return;  // need ~35.2 MB scratch

    float* Zr    = ws + ZR_OFF;
    float* h     = ws + ZR_OFF;     // alias: h live only after Zr dead
    float* rsA   = ws + RSA_OFF;
    float* Q     = ws + Q_OFF;
    float* ce    = ws + CE_OFF;
    float* bias0 = ws + B0_OFF;
    float* C0    = ws + C0_OFF;
    float* C1    = ws + C1_OFF;
    float* U     = ws + U_OFF;
    float* sg    = ws + SG_OFF;
    float* r1    = ws + R1_OFF;
    float* r2    = ws + R2_OFF;
    float* x2    = ws + X2_OFF;
    float* x2n   = ws + X2N_OFF;

    p0_const_k<<<36, 256, 0, stream>>>(B1g, absB1, B2g, C0, C1, U, sg, r1, r2);
    p1_q_k<<<384, 256, 0, stream>>>(wv0_w, wein_w, out_w, Q);
    p2_misc_k<<<1, 256, 0, stream>>>(wv0_b, wein_b, out_w, out_b, ce, bias0);
    k1_build<<<256, 256, 0, stream>>>(x, mask, B1g, e_i, e_j, t_ij, t_jk, t_ik,
                                      geom_w, geom_b, log_sc, n1_g, n1_b,
                                      C0, C1, U, sg, r1, r2, Zr, rsA);
    // attn GEMM: x2 = Zr @ Q + bias0 + rsA*ce + x
    gemm_tile<0><<<dim3(4, 64), 256, 0, stream>>>(Zr, 1536, Q, 256, 96,
                                                  bias0, rsA, ce, x, x2, 256);
    ln_rows<<<256, 256, 0, stream>>>(x2, n2_g, n2_b, x2n);
    // FFN1: h = gelu(x2n @ ffn1_w + ffn1_b)
    gemm_tile<1><<<dim3(16, 64), 256, 0, stream>>>(x2n, 256, ffn1_w, 1024, 16,
                                                   ffn1_b, nullptr, nullptr, nullptr, h, 1024);
    // FFN2: out = x2 + h @ ffn2_w + ffn2_b
    gemm_tile<2><<<dim3(4, 64), 256, 0, stream>>>(h, 1024, ffn2_w, 256, 64,
                                                  ffn2_b, x2, nullptr, nullptr, out, 256);
}

// Round 2
// 223.853 us; speedup vs baseline: 1.4573x; 1.4573x over previous
//
#include <hip/hip_runtime.h>
#include <math.h>

#define TAUF  1.0e-4f
#define LNEPS 1.0e-5f

typedef __bf16 bf16x8 __attribute__((ext_vector_type(8)));
typedef float  f32x4  __attribute__((ext_vector_type(4)));

static __device__ __forceinline__ unsigned short f2bf(float f) {
    union { float f; unsigned u; } v; v.f = f;
    unsigned r = v.u + 0x7fffu + ((v.u >> 16) & 1u);
    return (unsigned short)(r >> 16);
}
static __device__ __forceinline__ float bf2f(unsigned short h) {
    union { unsigned u; float f; } v; v.u = ((unsigned)h) << 16;
    return v.f;
}

// ---------------- workspace layout (float offsets, all 16B-aligned) ----------------
static const unsigned O_OFF   = 0u;         // 256*6*256 f32            = 393216
static const unsigned RSA_OFF = 393216u;    // 256*48
static const unsigned CE_OFF  = 405504u;    // 3*256
static const unsigned B0_OFF  = 406272u;    // 256
static const unsigned C0_OFF  = 406528u;    // 256
static const unsigned C1_OFF  = 406784u;    // 256
static const unsigned U_OFF   = 407040u;    // 16*560
static const unsigned SG_OFF  = 416000u;    // 560
static const unsigned R1_OFF  = 416560u;    // 16
static const unsigned R2_OFF  = 416576u;    // 16
static const unsigned X2_OFF  = 416768u;    // 4096*256 f32             -> 1465344
static const unsigned QT_OFF  = 1465344u;   // 1536*256 bf16 (196608 f) -> 1661952
static const unsigned W1T_OFF = 1661952u;   // 1024*256 bf16 (131072 f) -> 1793024
static const unsigned W2T_OFF = 1793024u;   // 256*1024 bf16 (131072 f) -> 1924096
static const unsigned XNB_OFF = 1924096u;   // 4096*256 bf16 (524288 f) -> 2448384
static const unsigned X2N_OFF = 2448384u;   // 4096*256 bf16 (524288 f) -> 2972672
static const unsigned Y_OFF   = 2972672u;   // 4096*1536 bf16 (3145728) -> 6118400
static const unsigned H_OFF   = 6118400u;   // 4096*1024 bf16 (2097152) -> 8215552
static const unsigned WS_FLOATS = 8215552u; // ~32.9 MB

// ---------------- constants of the complex ----------------
__launch_bounds__(256)
__global__ void p0_const_k(const float* __restrict__ B1g, const float* __restrict__ absB1,
                           const float* __restrict__ B2g,
                           float* __restrict__ C0, float* __restrict__ C1,
                           float* __restrict__ U, float* __restrict__ sigma,
                           float* __restrict__ r1, float* __restrict__ r2)
{
    int tid = threadIdx.x;
    if (blockIdx.x == 0) {
        int p = tid >> 4, q = tid & 15;
        float c0 = 0.f, c1 = 0.f;
        for (int e = 0; e < 120; ++e) {
            float ap = absB1[p*120+e];
            c0 += ap * B1g[q*120+e];
            c1 += ap * absB1[q*120+e];
        }
        C0[tid] = c0; C1[tid] = c1;
        if (tid < 16) {
            float a = 0.f, b = 0.f;
            for (int e = 0; e < 120; ++e) { a += B1g[tid*120+e]; b += absB1[tid*120+e]; }
            r1[tid] = a; r2[tid] = b;
        }
        for (int t = tid; t < 560; t += 256) {
            float s = 0.f;
            for (int e = 0; e < 120; ++e) s += B2g[e*560+t];
            sigma[t] = s;
        }
    } else {
        int idx = (blockIdx.x - 1) * 256 + tid;       // 0..8959
        int p = idx / 560, t = idx % 560;
        float u = 0.f;
        for (int e = 0; e < 120; ++e) u += absB1[p*120+e] * B2g[e*560+t];
        U[idx] = u;
    }
}

// ---------------- Q~t[blk*256+o][c'] = sum_d' Wsel[c', s*256+d'] * out_w[blk*256+d', o]  (bf16) ----------------
__launch_bounds__(256)
__global__ void p1_q_k(const float* __restrict__ wv0_w, const float* __restrict__ wein_w,
                       const float* __restrict__ out_w, unsigned short* __restrict__ Qt)
{
    int r0  = blockIdx.x * 4;            // 4 c'-rows per block, grid = 384
    int blk = r0 >> 8;
    int s   = (blk < 3) ? blk : blk - 3;
    const float* Wsel = (blk < 3) ? wv0_w : wein_w;
    int cp0 = r0 & 255;
    int o = threadIdx.x;
    float a0 = 0.f, a1 = 0.f, a2 = 0.f, a3 = 0.f;
    for (int c = 0; c < 256; ++c) {
        float ow = out_w[(size_t)(blk*256 + c)*256 + o];
        a0 += Wsel[(size_t)(cp0+0)*768 + s*256 + c] * ow;
        a1 += Wsel[(size_t)(cp0+1)*768 + s*256 + c] * ow;
        a2 += Wsel[(size_t)(cp0+2)*768 + s*256 + c] * ow;
        a3 += Wsel[(size_t)(cp0+3)*768 + s*256 + c] * ow;
    }
    ushort4 pk;
    pk.x = f2bf(a0); pk.y = f2bf(a1); pk.z = f2bf(a2); pk.w = f2bf(a3);
    *(ushort4*)(Qt + (size_t)(blk*256 + o)*256 + cp0) = pk;
}

// ---------------- bias folding ----------------
__launch_bounds__(256)
__global__ void p2_misc_k(const float* __restrict__ wv0_b, const float* __restrict__ wein_b,
                          const float* __restrict__ out_w, const float* __restrict__ out_b,
                          float* __restrict__ ce, float* __restrict__ bias0)
{
    int o = threadIdx.x;
    float acc = 0.f;
    for (int r = 0; r < 768; ++r) acc += wv0_b[r] * out_w[(size_t)r*256 + o];
    bias0[o] = out_b[o] + TAUF * acc;
    for (int s = 0; s < 3; ++s) {
        float a2 = 0.f;
        for (int c = 0; c < 256; ++c)
            a2 += wein_b[s*256 + c] * out_w[(size_t)(768 + s*256 + c)*256 + o];
        ce[s*256 + o] = a2;
    }
}

// ---------------- transpose + f32->bf16 convert: in[R][C] f32 -> out[C][R] bf16 ----------------
__launch_bounds__(256)
__global__ void tconv_k(const float* __restrict__ in, int R, int C, unsigned short* __restrict__ out)
{
    __shared__ float tile[32][33];
    int c0 = blockIdx.x * 32, r0 = blockIdx.y * 32;
    int tx = threadIdx.x & 31, ty = threadIdx.x >> 5;   // ty 0..7
    #pragma unroll
    for (int i = 0; i < 4; ++i)
        tile[ty + i*8][tx] = in[(size_t)(r0 + ty + i*8)*C + c0 + tx];
    __syncthreads();
    #pragma unroll
    for (int i = 0; i < 4; ++i)
        out[(size_t)(c0 + ty + i*8)*R + r0 + tx] = f2bf(tile[tx][ty + i*8]);
}

// ---------------- per-batch: LN1, xnb(bf16), P, W1, W2, six 16x16 operators, rsA ----------------
__launch_bounds__(256)
__global__ void k1_build(const float* __restrict__ x, const float* __restrict__ mask,
                         const float* __restrict__ B1g,
                         const int* __restrict__ e_i, const int* __restrict__ e_j,
                         const int* __restrict__ t_ij, const int* __restrict__ t_jk,
                         const int* __restrict__ t_ik,
                         const float* __restrict__ geom_w, const float* __restrict__ geom_b,
                         const float* __restrict__ log_sc,
                         const float* __restrict__ n1_g, const float* __restrict__ n1_b,
                         const float* __restrict__ C0, const float* __restrict__ C1,
                         const float* __restrict__ U, const float* __restrict__ sigma,
                         const float* __restrict__ r1, const float* __restrict__ r2,
                         float* __restrict__ Og, float* __restrict__ rsA,
                         unsigned short* __restrict__ xnb)
{
    __shared__ float sxn[16][256];
    __shared__ float sP[16][16];
    __shared__ float sW1[3][120];
    __shared__ float sW2[3][560];
    __shared__ float sB1[16*121];
    __shared__ float sU[16*561];
    __shared__ float sMask[16];

    int bb = blockIdx.x, tid = threadIdx.x;
    int r = tid >> 4, g = tid & 15;

    // ---- LayerNorm 1 ----
    {
        const float* row = x + ((size_t)bb*16 + r)*256;
        float v[16]; float sum = 0.f, ss = 0.f;
        #pragma unroll
        for (int m = 0; m < 16; ++m) { float t = row[g*16 + m]; v[m] = t; sum += t; ss += t*t; }
        #pragma unroll
        for (int o = 8; o; o >>= 1) { sum += __shfl_xor(sum, o); ss += __shfl_xor(ss, o); }
        float mean = sum * (1.f/256.f);
        float rstd = rsqrtf(ss*(1.f/256.f) - mean*mean + LNEPS);
        #pragma unroll
        for (int m = 0; m < 16; ++m) {
            int c = g*16 + m;
            sxn[r][c] = (v[m]-mean)*rstd*n1_g[c] + n1_b[c];
        }
        if (tid < 16) sMask[tid] = mask[bb*16 + tid];
    }
    for (int i = tid; i < 16*120; i += 256) sB1[(i/120)*121 + (i%120)] = B1g[i];
    for (int i = tid; i < 16*560; i += 256) sU[(i/560)*561 + (i%560)] = U[i];
    __syncthreads();

    // xnb (bf16) for the MFMA Y-GEMM
    #pragma unroll
    for (int l = 0; l < 16; ++l)
        xnb[((size_t)bb*16 + l)*256 + tid] = f2bf(sxn[l][tid]);

    // ---- P = xn @ geom_w + geom_b ----
    {
        float acc = geom_b[g];
        for (int c = 0; c < 256; ++c) acc += sxn[r][c] * geom_w[c*16 + g];
        sP[r][g] = acc;
    }
    __syncthreads();

    // ---- W1 ----
    float denom[3];
    #pragma unroll
    for (int s = 0; s < 3; ++s) { float sc = expf(log_sc[s]); denom[s] = 2.f*sc*sc + 1e-8f; }
    if (tid < 120) {
        int e = tid, i0 = e_i[e], j0 = e_j[e];
        float d2 = 0.f;
        #pragma unroll
        for (int m = 0; m < 16; ++m) { float dd = sP[i0][m] - sP[j0][m]; d2 += dd*dd; }
        float mm = sMask[i0]*sMask[j0];
        d2 *= mm*mm;
        #pragma unroll
        for (int s = 0; s < 3; ++s) sW1[s][e] = expf(-d2/denom[s]) * mm;
    }
    __syncthreads();

    // ---- W2 ----
    for (int t = tid; t < 560; t += 256) {
        int a = t_ij[t], b2 = t_jk[t], c2 = t_ik[t];
        #pragma unroll
        for (int s = 0; s < 3; ++s) sW2[s][t] = sW1[s][a]*sW1[s][b2]*sW1[s][c2];
    }
    __syncthreads();

    // ---- operators (thread -> (k,l)); write straight to global ----
    int k = tid >> 4, l = tid & 15;
    #pragma unroll
    for (int s = 0; s < 3; ++s) {
        float acc = 0.f;
        for (int e = 0; e < 120; ++e) acc += sW1[s][e]*sB1[k*121+e]*sB1[l*121+e];
        Og[(size_t)bb*1536 + s*256 + tid] = acc + ((k == l) ? TAUF : 0.f);
    }
    float hbase;
    {
        float hd = 0.f;
        #pragma unroll
        for (int p = 0; p < 16; ++p) hd += C0[k*16+p]*sMask[p]*C0[l*16+p];
        hbase = hd + TAUF*C1[k*16+l];
    }
    #pragma unroll
    for (int s = 0; s < 3; ++s) {
        float acc = 0.f;
        for (int t = 0; t < 560; ++t) acc += sW2[s][t]*sU[k*561+t]*sU[l*561+t];
        Og[(size_t)bb*1536 + (3+s)*256 + tid] = hbase + acc;
    }
    if (tid < 48) {
        int s = tid / 16, kk = tid & 15;
        float acc = TAUF * r2[kk];
        #pragma unroll
        for (int p = 0; p < 16; ++p) acc += C0[kk*16+p]*sMask[p]*r1[p];
        for (int t = 0; t < 560; ++t) acc += sU[kk*561+t]*sW2[s][t]*sigma[t];
        rsA[bb*48 + s*16 + kk] = acc;
    }
}

// ---------------- MFMA bf16 GEMM: C[M][N] = A[M][K] @ Bt[N][K]^T, BK=64, BN=64, 4 waves ----------------
// EPI 0: write bf16 (no bias) | EPI 1: +bias, exact gelu, write bf16 | EPI 2: +bias +resid, write f32
template<int BM, int EPI>
__launch_bounds__(256)
__global__ void gemm_mfma(const unsigned short* __restrict__ A, int lda,
                          const unsigned short* __restrict__ Bt, int ldb,
                          int nk,                 // K/64
                          const float* __restrict__ bias,
                          const float* __restrict__ resid,
                          void* __restrict__ Cout, int ldc)
{
    constexpr int WM = BM/2;
    constexpr int MI = WM/16;
    __shared__ unsigned short sA[2][BM*64];
    __shared__ unsigned short sB[2][64*64];
    const int tid = threadIdx.x;
    const int row0 = blockIdx.y * BM, col0 = blockIdx.x * 64;
    const int lane = tid & 63, w = tid >> 6;
    const int wr = w >> 1, wc = w & 1;
    const int rr = lane & 15, kq = lane >> 4;
    const int lrow = tid >> 3, lkg = tid & 7;

    f32x4 acc[MI][2];
    #pragma unroll
    for (int i = 0; i < MI; ++i) { acc[i][0] = 0.0f; acc[i][1] = 0.0f; }

    uint4 ra[2], rb[2];
    auto loadAB = [&](int kt) {
        size_t abase = (size_t)(row0 + lrow)*lda + kt*64 + lkg*8;
        ra[0] = *(const uint4*)(A + abase);
        if constexpr (BM == 64) ra[1] = *(const uint4*)(A + abase + (size_t)32*lda);
        size_t bbase = (size_t)(col0 + lrow)*ldb + kt*64 + lkg*8;
        rb[0] = *(const uint4*)(Bt + bbase);
        rb[1] = *(const uint4*)(Bt + bbase + (size_t)32*ldb);
    };
    auto store = [&](int buf) {
        int swz = (lkg ^ (lrow & 7)) * 8;
        *(uint4*)&sA[buf][lrow*64 + swz] = ra[0];
        if constexpr (BM == 64) *(uint4*)&sA[buf][(lrow+32)*64 + swz] = ra[1];
        *(uint4*)&sB[buf][lrow*64 + swz] = rb[0];
        *(uint4*)&sB[buf][(lrow+32)*64 + swz] = rb[1];
    };

    loadAB(0);
    store(0);
    __syncthreads();

    for (int kt = 0; kt < nk; ++kt) {
        int cur = kt & 1;
        bool more = (kt + 1 < nk);
        if (more) loadAB(kt + 1);
        #pragma unroll
        for (int ks = 0; ks < 2; ++ks) {
            bf16x8 af[MI], bf[2];
            #pragma unroll
            for (int i = 0; i < MI; ++i) {
                int row = wr*WM + i*16 + rr;
                int kg = ks*4 + kq;
                af[i] = *(const bf16x8*)&sA[cur][row*64 + ((kg ^ (row & 7))*8)];
            }
            #pragma unroll
            for (int j = 0; j < 2; ++j) {
                int n = wc*32 + j*16 + rr;
                int kg = ks*4 + kq;
                bf[j] = *(const bf16x8*)&sB[cur][n*64 + ((kg ^ (n & 7))*8)];
            }
            #pragma unroll
            for (int i = 0; i < MI; ++i)
                #pragma unroll
                for (int j = 0; j < 2; ++j)
                    acc[i][j] = __builtin_amdgcn_mfma_f32_16x16x32_bf16(af[i], bf[j], acc[i][j], 0, 0, 0);
        }
        __syncthreads();
        if (more) { store(cur ^ 1); __syncthreads(); }
    }

    // epilogue: C/D layout col=lane&15, row=(lane>>4)*4+e  [m89-verified]
    #pragma unroll
    for (int i = 0; i < MI; ++i) {
        #pragma unroll
        for (int j = 0; j < 2; ++j) {
            #pragma unroll
            for (int e = 0; e < 4; ++e) {
                int row = row0 + wr*WM + i*16 + kq*4 + e;
                int col = col0 + wc*32 + j*16 + rr;
                float v = acc[i][j][e];
                if (EPI == 0) {
                    ((unsigned short*)Cout)[(size_t)row*ldc + col] = f2bf(v);
                } else if (EPI == 1) {
                    v += bias[col];
                    v = 0.5f * v * (1.f + erff(v * 0.70710678118654752f));
                    ((unsigned short*)Cout)[(size_t)row*ldc + col] = f2bf(v);
                } else {
                    v += bias[col] + resid[(size_t)row*ldc + col];
                    ((float*)Cout)[(size_t)row*ldc + col] = v;
                }
            }
        }
    }
}

// ---------------- per-batch apply: x2 = sum_blk O_blk @ Y_blk + bias0 + rsA*ce + x; fused LN2 -> x2n bf16 ----------------
__launch_bounds__(256)
__global__ void k2_apply(const unsigned short* __restrict__ Y, const float* __restrict__ Og,
                         const float* __restrict__ rsA, const float* __restrict__ bias0,
                         const float* __restrict__ ce, const float* __restrict__ x,
                         const float* __restrict__ n2g, const float* __restrict__ n2b,
                         float* __restrict__ x2, unsigned short* __restrict__ x2n)
{
    __shared__ unsigned short sY[16*1536];   // 48 KB
    __shared__ float sO[1536];               // 6 KB
    __shared__ float sX[16][257];            // 16.4 KB
    int bb = blockIdx.x, tid = threadIdx.x;

    #pragma unroll
    for (int i = 0; i < 12; ++i) {
        int idx = i*256 + tid;               // ushort8 index, 3072 total
        *(uint4*)&sY[idx*8] = *(const uint4*)(Y + (size_t)bb*16*1536 + (size_t)idx*8);
    }
    #pragma unroll
    for (int i = 0; i < 6; ++i) sO[i*256 + tid] = Og[(size_t)bb*1536 + i*256 + tid];
    __syncthreads();

    int o = tid;
    float acc[16];
    #pragma unroll
    for (int k = 0; k < 16; ++k) acc[k] = 0.f;
    for (int blk = 0; blk < 6; ++blk) {
        #pragma unroll
        for (int l = 0; l < 16; ++l) {
            float y = bf2f(sY[l*1536 + blk*256 + o]);
            #pragma unroll
            for (int k = 0; k < 16; ++k) acc[k] += sO[blk*256 + k*16 + l] * y;
        }
    }
    float b0 = bias0[o], c0 = ce[o], c1 = ce[256+o], c2 = ce[512+o];
    #pragma unroll
    for (int k = 0; k < 16; ++k) {
        float v = acc[k] + b0
                + rsA[bb*48 +      k] * c0
                + rsA[bb*48 + 16 + k] * c1
                + rsA[bb*48 + 32 + k] * c2
                + x[((size_t)bb*16 + k)*256 + o];
        sX[k][o] = v;
        x2[((size_t)bb*16 + k)*256 + o] = v;
    }
    __syncthreads();

    int r = tid >> 4, g = tid & 15;
    float vv[16]; float sum = 0.f, ss = 0.f;
    #pragma unroll
    for (int m = 0; m < 16; ++m) { float t = sX[r][g*16 + m]; vv[m] = t; sum += t; ss += t*t; }
    #pragma unroll
    for (int off = 8; off; off >>= 1) { sum += __shfl_xor(sum, off); ss += __shfl_xor(ss, off); }
    float mean = sum * (1.f/256.f);
    float rstd = rsqrtf(ss*(1.f/256.f) - mean*mean + LNEPS);
    #pragma unroll
    for (int m = 0; m < 16; ++m) {
        int c = g*16 + m;
        x2n[((size_t)bb*16 + r)*256 + c] = f2bf((vv[m]-mean)*rstd*n2g[c] + n2b[c]);
    }
}

extern "C" void kernel_launch(void* const* d_in, const int* in_sizes, int n_in,
                              void* d_out, int out_size, void* d_ws, size_t ws_size,
                              hipStream_t stream)
{
    (void)in_sizes; (void)n_in; (void)out_size;
    const float* x      = (const float*)d_in[0];
    const float* mask   = (const float*)d_in[1];
    const float* B1g    = (const float*)d_in[2];
    const float* B2g    = (const float*)d_in[3];
    const float* absB1  = (const float*)d_in[4];
    const int*   e_i    = (const int*)d_in[5];
    const int*   e_j    = (const int*)d_in[6];
    const int*   t_ij   = (const int*)d_in[7];
    const int*   t_jk   = (const int*)d_in[8];
    const int*   t_ik   = (const int*)d_in[9];
    const float* geom_w = (const float*)d_in[10];
    const float* geom_b = (const float*)d_in[11];
    const float* log_sc = (const float*)d_in[12];
    const float* wv0_w  = (const float*)d_in[13];
    const float* wv0_b  = (const float*)d_in[14];
    const float* wein_w = (const float*)d_in[15];
    const float* wein_b = (const float*)d_in[16];
    const float* out_w  = (const float*)d_in[17];
    const float* out_b  = (const float*)d_in[18];
    const float* n1_g   = (const float*)d_in[19];
    const float* n1_b   = (const float*)d_in[20];
    const float* n2_g   = (const float*)d_in[21];
    const float* n2_b   = (const float*)d_in[22];
    const float* ffn1_w = (const float*)d_in[23];
    const float* ffn1_b = (const float*)d_in[24];
    const float* ffn2_w = (const float*)d_in[25];
    const float* ffn2_b = (const float*)d_in[26];

    float* out = (float*)d_out;
    float* ws  = (float*)d_ws;
    if (ws_size < (size_t)WS_FLOATS * sizeof(float)) return;

    float* Og    = ws + O_OFF;
    float* rsA   = ws + RSA_OFF;
    float* ce    = ws + CE_OFF;
    float* bias0 = ws + B0_OFF;
    float* C0    = ws + C0_OFF;
    float* C1    = ws + C1_OFF;
    float* U     = ws + U_OFF;
    float* sg    = ws + SG_OFF;
    float* r1    = ws + R1_OFF;
    float* r2    = ws + R2_OFF;
    float* x2    = ws + X2_OFF;
    unsigned short* Qt  = (unsigned short*)(ws + QT_OFF);
    unsigned short* w1t = (unsigned short*)(ws + W1T_OFF);
    unsigned short* w2t = (unsigned short*)(ws + W2T_OFF);
    unsigned short* xnb = (unsigned short*)(ws + XNB_OFF);
    unsigned short* x2n = (unsigned short*)(ws + X2N_OFF);
    unsigned short* Yb  = (unsigned short*)(ws + Y_OFF);
    unsigned short* hb  = (unsigned short*)(ws + H_OFF);

    p0_const_k<<<36, 256, 0, stream>>>(B1g, absB1, B2g, C0, C1, U, sg, r1, r2);
    p1_q_k<<<384, 256, 0, stream>>>(wv0_w, wein_w, out_w, Qt);
    p2_misc_k<<<1, 256, 0, stream>>>(wv0_b, wein_b, out_w, out_b, ce, bias0);
    tconv_k<<<dim3(32, 8), 256, 0, stream>>>(ffn1_w, 256, 1024, w1t);   // [256][1024] -> [1024][256]
    tconv_k<<<dim3(8, 32), 256, 0, stream>>>(ffn2_w, 1024, 256, w2t);   // [1024][256] -> [256][1024]
    k1_build<<<256, 256, 0, stream>>>(x, mask, B1g, e_i, e_j, t_ij, t_jk, t_ik,
                                      geom_w, geom_b, log_sc, n1_g, n1_b,
                                      C0, C1, U, sg, r1, r2, Og, rsA, xnb);
    // Y = xnb @ Qt^T   (4096x1536, K=256) -> bf16
    gemm_mfma<64, 0><<<dim3(24, 64), 256, 0, stream>>>(xnb, 256, Qt, 256, 4,
                                                       nullptr, nullptr, Yb, 1536);
    // x2 = sum_blk O_blk @ Y_blk + bias0 + rsA*ce + x ; LN2 -> x2n
    k2_apply<<<256, 256, 0, stream>>>(Yb, Og, rsA, bias0, ce, x, n2_g, n2_b, x2, x2n);
    // h = gelu(x2n @ w1t^T + ffn1_b)   (4096x1024, K=256) -> bf16
    gemm_mfma<64, 1><<<dim3(16, 64), 256, 0, stream>>>(x2n, 256, w1t, 256, 4,
                                                       ffn1_b, nullptr, hb, 1024);
    // out = x2 + h @ w2t^T + ffn2_b    (4096x256, K=1024) -> f32
    gemm_mfma<32, 2><<<dim3(4, 128), 256, 0, stream>>>(hb, 1024, w2t, 1024, 16,
                                                       ffn2_b, x2, out, 256);
}

// Round 3
// 153.461 us; speedup vs baseline: 2.1257x; 1.4587x over previous
//
#include <hip/hip_runtime.h>
#include <math.h>

#define TAUF  1.0e-4f
#define LNEPS 1.0e-5f

typedef __bf16 bf16x8 __attribute__((ext_vector_type(8)));
typedef float  f32x4  __attribute__((ext_vector_type(4)));

union U4 { uint4 u4; unsigned short us[8]; bf16x8 bv; };

static __device__ __forceinline__ unsigned short f2bf(float f) {
    union { float f; unsigned u; } v; v.f = f;
    unsigned r = v.u + 0x7fffu + ((v.u >> 16) & 1u);
    return (unsigned short)(r >> 16);
}
static __device__ __forceinline__ float bf2f(unsigned short h) {
    union { unsigned u; float f; } v; v.u = ((unsigned)h) << 16;
    return v.f;
}

// ---------------- workspace layout (float offsets, all 16B-aligned) ----------------
static const unsigned O_OFF    = 0u;         // 256*6*256 f32           -> 393216
static const unsigned RSA_OFF  = 393216u;    // 256*48                  -> 405504
static const unsigned CE_OFF   = 405504u;    // 3*256                   -> 406272
static const unsigned B0_OFF   = 406272u;    // 256                     -> 406528
static const unsigned C0_OFF   = 406528u;    // 256                     -> 406784
static const unsigned C1_OFF   = 406784u;    // 256                     -> 407040
static const unsigned U_OFF    = 407040u;    // 16*560                  -> 416000
static const unsigned SG_OFF   = 416000u;    // 560                     -> 416560
static const unsigned R1_OFF   = 416560u;    // 16                      -> 416576
static const unsigned R2_OFF   = 416576u;    // 16                      -> 416592
static const unsigned UF_OFF   = 416592u;    // 18*64 uint4 (4608 f)    -> 421200
static const unsigned B1F_OFF  = 421200u;    // 4*64 uint4  (1024 f)    -> 422224
static const unsigned WVB_OFF  = 422224u;    // 196608 bf16 (98304 f)   -> 520528
static const unsigned WEB_OFF  = 520528u;    // 196608 bf16 (98304 f)   -> 618832
static const unsigned OWT_OFF  = 618832u;    // 393216 bf16 (196608 f)  -> 815440
static const unsigned X2_OFF   = 815440u;    // 4096*256 f32            -> 1864016
static const unsigned QT_OFF   = 1864016u;   // 393216 bf16 (196608 f)  -> 2060624
static const unsigned W1T_OFF  = 2060624u;   // 262144 bf16 (131072 f)  -> 2191696
static const unsigned W2T_OFF  = 2191696u;   // 262144 bf16 (131072 f)  -> 2322768
static const unsigned XNB_OFF  = 2322768u;   // 1048576 bf16 (524288 f) -> 2847056
static const unsigned X2N_OFF  = 2847056u;   // 1048576 bf16 (524288 f) -> 3371344
static const unsigned Y_OFF    = 3371344u;   // 6291456 bf16 (3145728)  -> 6517072
static const unsigned H_OFF    = 6517072u;   // 4194304 bf16 (2097152)  -> 8614224
static const unsigned WS_FLOATS = 8614224u;  // ~34.5 MB

// ================= wprep: all x-independent prep in ONE launch =================
// b <   96 : f32->bf16 convert wv0_w -> wvb
// b <  192 : f32->bf16 convert wein_w -> weinb
// b <  576 : per-blk transpose out_w -> owTB bf16   (6 x 256x256)
// b <  832 : transpose ffn1_w [256][1024] -> w1t [1024][256] bf16
// b < 1088 : transpose ffn2_w [1024][256] -> w2t [256][1024] bf16
// b < 1092 : bias folds (ce, bias0)
// b < 1128 : complex constants (C0,C1,r1,r2,sigma,U)
__launch_bounds__(256)
__global__ void wprep_k(const float* __restrict__ wv0_w, const float* __restrict__ wein_w,
                        const float* __restrict__ out_w,
                        const float* __restrict__ ffn1_w, const float* __restrict__ ffn2_w,
                        const float* __restrict__ wv0_b, const float* __restrict__ wein_b,
                        const float* __restrict__ out_b,
                        const float* __restrict__ B1g, const float* __restrict__ absB1,
                        const float* __restrict__ B2g,
                        unsigned short* __restrict__ wvb, unsigned short* __restrict__ weinb,
                        unsigned short* __restrict__ owTB,
                        unsigned short* __restrict__ w1t, unsigned short* __restrict__ w2t,
                        float* __restrict__ ce, float* __restrict__ bias0,
                        float* __restrict__ C0, float* __restrict__ C1,
                        float* __restrict__ U, float* __restrict__ sigma,
                        float* __restrict__ r1, float* __restrict__ r2)
{
    __shared__ float tile[32][33];
    int b = blockIdx.x, tid = threadIdx.x;
    if (b < 192) {
        const float* src = (b < 96) ? wv0_w : wein_w;
        unsigned short* dst = (b < 96) ? wvb : weinb;
        int base = ((b % 96) * 256 + tid) * 8;
        float4 a = *(const float4*)(src + base);
        float4 c = *(const float4*)(src + base + 4);
        U4 o;
        o.us[0]=f2bf(a.x); o.us[1]=f2bf(a.y); o.us[2]=f2bf(a.z); o.us[3]=f2bf(a.w);
        o.us[4]=f2bf(c.x); o.us[5]=f2bf(c.y); o.us[6]=f2bf(c.z); o.us[7]=f2bf(c.w);
        *(uint4*)(dst + base) = o.u4;
    } else if (b < 576) {
        int bi = b - 192;
        int z = bi >> 6; bi &= 63;
        int r0 = (bi >> 3) * 32, c0 = (bi & 7) * 32;
        int tx = tid & 31, ty = tid >> 5;
        #pragma unroll
        for (int i = 0; i < 4; ++i)
            tile[ty + i*8][tx] = out_w[(size_t)(z*256 + r0 + ty + i*8)*256 + c0 + tx];
        __syncthreads();
        #pragma unroll
        for (int i = 0; i < 4; ++i)
            owTB[(size_t)(z*256 + c0 + ty + i*8)*256 + r0 + tx] = f2bf(tile[tx][ty + i*8]);
    } else if (b < 832) {
        int bi = b - 576;                 // R=256, C=1024: c0 = (bi%32)*32, r0=(bi/32)*32
        int c0 = (bi & 31) * 32, r0 = (bi >> 5) * 32;
        int tx = tid & 31, ty = tid >> 5;
        #pragma unroll
        for (int i = 0; i < 4; ++i)
            tile[ty + i*8][tx] = ffn1_w[(size_t)(r0 + ty + i*8)*1024 + c0 + tx];
        __syncthreads();
        #pragma unroll
        for (int i = 0; i < 4; ++i)
            w1t[(size_t)(c0 + ty + i*8)*256 + r0 + tx] = f2bf(tile[tx][ty + i*8]);
    } else if (b < 1088) {
        int bi = b - 832;                 // R=1024, C=256: c0 = (bi%8)*32, r0=(bi/8)*32
        int c0 = (bi & 7) * 32, r0 = (bi >> 3) * 32;
        int tx = tid & 31, ty = tid >> 5;
        #pragma unroll
        for (int i = 0; i < 4; ++i)
            tile[ty + i*8][tx] = ffn2_w[(size_t)(r0 + ty + i*8)*256 + c0 + tx];
        __syncthreads();
        #pragma unroll
        for (int i = 0; i < 4; ++i)
            w2t[(size_t)(c0 + ty + i*8)*1024 + r0 + tx] = f2bf(tile[tx][ty + i*8]);
    } else if (b < 1092) {
        int which = b - 1088;
        int o = tid;
        if (which == 3) {
            float acc = 0.f;
            for (int r = 0; r < 768; ++r) acc += wv0_b[r] * out_w[(size_t)r*256 + o];
            bias0[o] = out_b[o] + TAUF * acc;
        } else {
            float a2 = 0.f;
            for (int c = 0; c < 256; ++c)
                a2 += wein_b[which*256 + c] * out_w[(size_t)(768 + which*256 + c)*256 + o];
            ce[which*256 + o] = a2;
        }
    } else {
        int sub = b - 1092;
        if (sub == 0) {
            int p = tid >> 4, q = tid & 15;
            float c0 = 0.f, c1 = 0.f;
            for (int e = 0; e < 120; ++e) {
                float ap = absB1[p*120+e];
                c0 += ap * B1g[q*120+e];
                c1 += ap * absB1[q*120+e];
            }
            C0[tid] = c0; C1[tid] = c1;
            if (tid < 16) {
                float a = 0.f, bb = 0.f;
                for (int e = 0; e < 120; ++e) { a += B1g[tid*120+e]; bb += absB1[tid*120+e]; }
                r1[tid] = a; r2[tid] = bb;
            }
            for (int t = tid; t < 560; t += 256) {
                float s = 0.f;
                for (int e = 0; e < 120; ++e) s += B2g[e*560+t];
                sigma[t] = s;
            }
        } else {
            int idx = (sub - 1) * 256 + tid;      // 0..8959 over 35 blocks
            int p = idx / 560, t = idx % 560;
            float u = 0.f;
            for (int e = 0; e < 120; ++e) u += absB1[p*120+e] * B2g[e*560+t];
            U[idx] = u;
        }
    }
}

// ============== p0b: MFMA operand fragments for U(+C0 ext) and B1, batch-invariant ==============
// frag layout for mfma_f32_16x16x32_bf16 A/B operands: lane holds row/col=lane&15, k=(lane>>4)*8+j
__launch_bounds__(64)
__global__ void p0b_k(const float* __restrict__ B1g, const float* __restrict__ Up,
                      const float* __restrict__ C0,
                      uint4* __restrict__ ufrag, uint4* __restrict__ b1frag)
{
    int lane = threadIdx.x;
    int b = blockIdx.x;
    int col = lane & 15, kq = lane >> 4;
    U4 o;
    if (b < 18) {
        int kt = b;
        #pragma unroll
        for (int j = 0; j < 8; ++j) {
            int t = kt*32 + kq*8 + j;
            float v = (t < 560) ? Up[col*560 + t] : C0[col*16 + (t - 560)];
            o.us[j] = f2bf(v);
        }
        ufrag[kt*64 + lane] = o.u4;
    } else {
        int kt = b - 18;
        #pragma unroll
        for (int j = 0; j < 8; ++j) {
            int e = kt*32 + kq*8 + j;
            float v = (e < 120) ? B1g[col*120 + e] : 0.f;
            o.us[j] = f2bf(v);
        }
        b1frag[kt*64 + lane] = o.u4;
    }
}

// ============== q_mfma: Qt[m][n] = sum_k owTB[m][k] * Wsel[n][s*256+k] (bf16 MFMA) ==============
__launch_bounds__(256)
__global__ void q_mfma_k(const unsigned short* __restrict__ owTB,
                         const unsigned short* __restrict__ wvb,
                         const unsigned short* __restrict__ weinb,
                         unsigned short* __restrict__ Qt)
{
    __shared__ unsigned short sA[2][64*64];
    __shared__ unsigned short sB[2][64*64];
    const int tid = threadIdx.x;
    const int row0 = blockIdx.y * 64, col0 = blockIdx.x * 64;
    const int blk = row0 >> 8;
    const int s = (blk < 3) ? blk : blk - 3;
    const unsigned short* A  = owTB;                          // lda 256
    const unsigned short* Bt = ((blk < 3) ? wvb : weinb) + s*256;  // ldb 768
    const int lane = tid & 63, w = tid >> 6;
    const int wr = w >> 1, wc = w & 1;
    const int rr = lane & 15, kq = lane >> 4;
    const int lrow = tid >> 3, lkg = tid & 7;

    f32x4 acc[2][2];
    #pragma unroll
    for (int i = 0; i < 2; ++i) { acc[i][0] = 0.0f; acc[i][1] = 0.0f; }

    uint4 ra[2], rb[2];
    auto loadAB = [&](int kt) {
        size_t abase = (size_t)(row0 + lrow)*256 + kt*64 + lkg*8;
        ra[0] = *(const uint4*)(A + abase);
        ra[1] = *(const uint4*)(A + abase + (size_t)32*256);
        size_t bbase = (size_t)(col0 + lrow)*768 + kt*64 + lkg*8;
        rb[0] = *(const uint4*)(Bt + bbase);
        rb[1] = *(const uint4*)(Bt + bbase + (size_t)32*768);
    };
    auto store = [&](int buf) {
        int swz = (lkg ^ (lrow & 7)) * 8;
        *(uint4*)&sA[buf][lrow*64 + swz] = ra[0];
        *(uint4*)&sA[buf][(lrow+32)*64 + swz] = ra[1];
        *(uint4*)&sB[buf][lrow*64 + swz] = rb[0];
        *(uint4*)&sB[buf][(lrow+32)*64 + swz] = rb[1];
    };

    loadAB(0); store(0); __syncthreads();
    for (int kt = 0; kt < 4; ++kt) {
        int cur = kt & 1;
        bool more = (kt + 1 < 4);
        if (more) loadAB(kt + 1);
        #pragma unroll
        for (int ks = 0; ks < 2; ++ks) {
            bf16x8 af[2], bfv[2];
            #pragma unroll
            for (int i = 0; i < 2; ++i) {
                int row = wr*32 + i*16 + rr;
                int kg = ks*4 + kq;
                af[i] = *(const bf16x8*)&sA[cur][row*64 + ((kg ^ (row & 7))*8)];
            }
            #pragma unroll
            for (int j = 0; j < 2; ++j) {
                int n = wc*32 + j*16 + rr;
                int kg = ks*4 + kq;
                bfv[j] = *(const bf16x8*)&sB[cur][n*64 + ((kg ^ (n & 7))*8)];
            }
            #pragma unroll
            for (int i = 0; i < 2; ++i)
                #pragma unroll
                for (int j = 0; j < 2; ++j)
                    acc[i][j] = __builtin_amdgcn_mfma_f32_16x16x32_bf16(af[i], bfv[j], acc[i][j], 0, 0, 0);
        }
        __syncthreads();
        if (more) { store(cur ^ 1); __syncthreads(); }
    }
    #pragma unroll
    for (int i = 0; i < 2; ++i)
        #pragma unroll
        for (int j = 0; j < 2; ++j)
            #pragma unroll
            for (int e = 0; e < 4; ++e) {
                int row = row0 + wr*32 + i*16 + kq*4 + e;
                int col = col0 + wc*32 + j*16 + rr;
                Qt[(size_t)row*256 + col] = f2bf(acc[i][j][e]);
            }
}

// ============== k1: per-batch LN1, xnb, P, W1, W2, MFMA operator build, rsA ==============
__launch_bounds__(256)
__global__ void k1_build(const float* __restrict__ x, const float* __restrict__ mask,
                         const int* __restrict__ e_i, const int* __restrict__ e_j,
                         const int* __restrict__ t_ij, const int* __restrict__ t_jk,
                         const int* __restrict__ t_ik,
                         const float* __restrict__ geom_w, const float* __restrict__ geom_b,
                         const float* __restrict__ log_sc,
                         const float* __restrict__ n1_g, const float* __restrict__ n1_b,
                         const float* __restrict__ C0, const float* __restrict__ C1,
                         const float* __restrict__ Up, const float* __restrict__ sg,
                         const float* __restrict__ r1, const float* __restrict__ r2,
                         const uint4* __restrict__ ufrag, const uint4* __restrict__ b1frag,
                         float* __restrict__ Og, float* __restrict__ rsA,
                         unsigned short* __restrict__ xnb)
{
    __shared__ float sxn[16][257];
    __shared__ float sP[16][17];
    __shared__ float sW1e[3][128];
    __shared__ float sW2e[3][576];
    __shared__ float sSig[560];
    __shared__ float sMask[16];
    __shared__ float sRs[240];

    int bb = blockIdx.x, tid = threadIdx.x;
    int r = tid >> 4, g = tid & 15;

    // ---- LayerNorm 1 ----
    {
        const float* row = x + ((size_t)bb*16 + r)*256;
        float v[16]; float sum = 0.f, ss = 0.f;
        #pragma unroll
        for (int m = 0; m < 16; ++m) { float t = row[g*16 + m]; v[m] = t; sum += t; ss += t*t; }
        #pragma unroll
        for (int o = 8; o; o >>= 1) { sum += __shfl_xor(sum, o); ss += __shfl_xor(ss, o); }
        float mean = sum * (1.f/256.f);
        float rstd = rsqrtf(ss*(1.f/256.f) - mean*mean + LNEPS);
        #pragma unroll
        for (int m = 0; m < 16; ++m) {
            int c = g*16 + m;
            sxn[r][c] = (v[m]-mean)*rstd*n1_g[c] + n1_b[c];
        }
        if (tid < 16) sMask[tid] = mask[bb*16 + tid];
    }
    for (int i = tid; i < 560; i += 256) sSig[i] = sg[i];
    __syncthreads();

    // xnb (bf16) for the Y-GEMM
    #pragma unroll
    for (int l = 0; l < 16; ++l)
        xnb[((size_t)bb*16 + l)*256 + tid] = f2bf(sxn[l][tid]);

    // ---- P = xn @ geom_w + geom_b (thread -> (r,g)) ----
    {
        float a0 = 0.f, a1 = 0.f, a2 = 0.f, a3 = 0.f;
        for (int c = 0; c < 256; c += 4) {
            a0 += sxn[r][c+0] * geom_w[(c+0)*16 + g];
            a1 += sxn[r][c+1] * geom_w[(c+1)*16 + g];
            a2 += sxn[r][c+2] * geom_w[(c+2)*16 + g];
            a3 += sxn[r][c+3] * geom_w[(c+3)*16 + g];
        }
        sP[r][g] = (a0+a1) + (a2+a3) + geom_b[g];
    }
    __syncthreads();

    // ---- W1 (3x120) + zero-pad to 128 ----
    if (tid < 128) {
        if (tid < 120) {
            int e = tid, i0 = e_i[e], j0 = e_j[e];
            float d2 = 0.f;
            #pragma unroll
            for (int m = 0; m < 16; ++m) { float dd = sP[i0][m] - sP[j0][m]; d2 += dd*dd; }
            float mm = sMask[i0]*sMask[j0];
            d2 *= mm*mm;
            #pragma unroll
            for (int s = 0; s < 3; ++s) {
                float sc = expf(log_sc[s]);
                sW1e[s][e] = expf(-d2/(2.f*sc*sc + 1e-8f)) * mm;
            }
        } else {
            #pragma unroll
            for (int s = 0; s < 3; ++s) sW1e[s][tid] = 0.f;
        }
    }
    __syncthreads();

    // ---- W2 (3x560) + mask extension (t 560..575) ----
    for (int t = tid; t < 560; t += 256) {
        int a = t_ij[t], b2 = t_jk[t], c2 = t_ik[t];
        #pragma unroll
        for (int s = 0; s < 3; ++s) sW2e[s][t] = sW1e[s][a]*sW1e[s][b2]*sW1e[s][c2];
    }
    if (tid < 48) {
        int s = tid >> 4, p = tid & 15;
        sW2e[s][560 + p] = sMask[p];
    }
    __syncthreads();

    // ---- MFMA operator build: waves 0-2 edge scale s=w; wave 3 all node scales ----
    int lane = tid & 63, w = tid >> 6;
    int rr = lane & 15, kq = lane >> 4;
    if (w < 3) {
        int s = w;
        f32x4 acc = {0.f, 0.f, 0.f, 0.f};
        for (int kt = 0; kt < 18; ++kt) {
            U4 ub; ub.u4 = ufrag[kt*64 + lane];
            const float4* w4 = (const float4*)&sW2e[s][kt*32 + kq*8];
            float4 wa = w4[0], wb = w4[1];
            U4 av;
            av.us[0] = f2bf(wa.x * bf2f(ub.us[0]));
            av.us[1] = f2bf(wa.y * bf2f(ub.us[1]));
            av.us[2] = f2bf(wa.z * bf2f(ub.us[2]));
            av.us[3] = f2bf(wa.w * bf2f(ub.us[3]));
            av.us[4] = f2bf(wb.x * bf2f(ub.us[4]));
            av.us[5] = f2bf(wb.y * bf2f(ub.us[5]));
            av.us[6] = f2bf(wb.z * bf2f(ub.us[6]));
            av.us[7] = f2bf(wb.w * bf2f(ub.us[7]));
            acc = __builtin_amdgcn_mfma_f32_16x16x32_bf16(av.bv, ub.bv, acc, 0, 0, 0);
        }
        #pragma unroll
        for (int e = 0; e < 4; ++e) {
            int row = kq*4 + e;
            Og[(size_t)bb*1536 + (3+s)*256 + row*16 + rr] = acc[e] + TAUF*C1[row*16 + rr];
        }
    } else {
        f32x4 acc3[3];
        acc3[0] = 0.f; acc3[1] = 0.f; acc3[2] = 0.f;
        for (int kt = 0; kt < 4; ++kt) {
            U4 ub; ub.u4 = b1frag[kt*64 + lane];
            float uf[8];
            #pragma unroll
            for (int j = 0; j < 8; ++j) uf[j] = bf2f(ub.us[j]);
            #pragma unroll
            for (int s = 0; s < 3; ++s) {
                const float4* w4 = (const float4*)&sW1e[s][kt*32 + kq*8];
                float4 wa = w4[0], wb = w4[1];
                U4 av;
                av.us[0] = f2bf(wa.x * uf[0]);
                av.us[1] = f2bf(wa.y * uf[1]);
                av.us[2] = f2bf(wa.z * uf[2]);
                av.us[3] = f2bf(wa.w * uf[3]);
                av.us[4] = f2bf(wb.x * uf[4]);
                av.us[5] = f2bf(wb.y * uf[5]);
                av.us[6] = f2bf(wb.z * uf[6]);
                av.us[7] = f2bf(wb.w * uf[7]);
                acc3[s] = __builtin_amdgcn_mfma_f32_16x16x32_bf16(av.bv, ub.bv, acc3[s], 0, 0, 0);
            }
        }
        #pragma unroll
        for (int s = 0; s < 3; ++s)
            #pragma unroll
            for (int e = 0; e < 4; ++e) {
                int row = kq*4 + e;
                Og[(size_t)bb*1536 + s*256 + row*16 + rr] = acc3[s][e] + ((row == rr) ? TAUF : 0.f);
            }
    }

    // ---- rsA partials: 240 threads = (s, k, chunk of 112) ----
    if (tid < 240) {
        int s = tid / 80, rem = tid % 80;
        int k = rem / 5, ch = rem % 5;
        float p = 0.f;
        int t0 = ch * 112;
        for (int i = 0; i < 112; ++i) {
            int t = t0 + i;
            p += sW2e[s][t] * sSig[t] * Up[k*560 + t];
        }
        sRs[(s*16 + k)*5 + ch] = p;
    }
    __syncthreads();
    if (tid < 48) {
        int k = tid & 15;
        float a = TAUF * r2[k];
        #pragma unroll
        for (int p = 0; p < 16; ++p) a += C0[k*16 + p] * sMask[p] * r1[p];
        #pragma unroll
        for (int ch = 0; ch < 5; ++ch) a += sRs[tid*5 + ch];
        rsA[bb*48 + tid] = a;
    }
}

// ---------------- MFMA bf16 GEMM (unchanged from R2, passing) ----------------
template<int BM, int EPI>
__launch_bounds__(256)
__global__ void gemm_mfma(const unsigned short* __restrict__ A, int lda,
                          const unsigned short* __restrict__ Bt, int ldb,
                          int nk,
                          const float* __restrict__ bias,
                          const float* __restrict__ resid,
                          void* __restrict__ Cout, int ldc)
{
    constexpr int WM = BM/2;
    constexpr int MI = WM/16;
    __shared__ unsigned short sA[2][BM*64];
    __shared__ unsigned short sB[2][64*64];
    const int tid = threadIdx.x;
    const int row0 = blockIdx.y * BM, col0 = blockIdx.x * 64;
    const int lane = tid & 63, w = tid >> 6;
    const int wr = w >> 1, wc = w & 1;
    const int rr = lane & 15, kq = lane >> 4;
    const int lrow = tid >> 3, lkg = tid & 7;

    f32x4 acc[MI][2];
    #pragma unroll
    for (int i = 0; i < MI; ++i) { acc[i][0] = 0.0f; acc[i][1] = 0.0f; }

    uint4 ra[2], rb[2];
    auto loadAB = [&](int kt) {
        size_t abase = (size_t)(row0 + lrow)*lda + kt*64 + lkg*8;
        ra[0] = *(const uint4*)(A + abase);
        if constexpr (BM == 64) ra[1] = *(const uint4*)(A + abase + (size_t)32*lda);
        size_t bbase = (size_t)(col0 + lrow)*ldb + kt*64 + lkg*8;
        rb[0] = *(const uint4*)(Bt + bbase);
        rb[1] = *(const uint4*)(Bt + bbase + (size_t)32*ldb);
    };
    auto store = [&](int buf) {
        int swz = (lkg ^ (lrow & 7)) * 8;
        *(uint4*)&sA[buf][lrow*64 + swz] = ra[0];
        if constexpr (BM == 64) *(uint4*)&sA[buf][(lrow+32)*64 + swz] = ra[1];
        *(uint4*)&sB[buf][lrow*64 + swz] = rb[0];
        *(uint4*)&sB[buf][(lrow+32)*64 + swz] = rb[1];
    };

    loadAB(0); store(0); __syncthreads();

    for (int kt = 0; kt < nk; ++kt) {
        int cur = kt & 1;
        bool more = (kt + 1 < nk);
        if (more) loadAB(kt + 1);
        #pragma unroll
        for (int ks = 0; ks < 2; ++ks) {
            bf16x8 af[MI], bfv[2];
            #pragma unroll
            for (int i = 0; i < MI; ++i) {
                int row = wr*WM + i*16 + rr;
                int kg = ks*4 + kq;
                af[i] = *(const bf16x8*)&sA[cur][row*64 + ((kg ^ (row & 7))*8)];
            }
            #pragma unroll
            for (int j = 0; j < 2; ++j) {
                int n = wc*32 + j*16 + rr;
                int kg = ks*4 + kq;
                bfv[j] = *(const bf16x8*)&sB[cur][n*64 + ((kg ^ (n & 7))*8)];
            }
            #pragma unroll
            for (int i = 0; i < MI; ++i)
                #pragma unroll
                for (int j = 0; j < 2; ++j)
                    acc[i][j] = __builtin_amdgcn_mfma_f32_16x16x32_bf16(af[i], bfv[j], acc[i][j], 0, 0, 0);
        }
        __syncthreads();
        if (more) { store(cur ^ 1); __syncthreads(); }
    }

    #pragma unroll
    for (int i = 0; i < MI; ++i) {
        #pragma unroll
        for (int j = 0; j < 2; ++j) {
            #pragma unroll
            for (int e = 0; e < 4; ++e) {
                int row = row0 + wr*WM + i*16 + kq*4 + e;
                int col = col0 + wc*32 + j*16 + rr;
                float v = acc[i][j][e];
                if (EPI == 0) {
                    ((unsigned short*)Cout)[(size_t)row*ldc + col] = f2bf(v);
                } else if (EPI == 1) {
                    v += bias[col];
                    v = 0.5f * v * (1.f + erff(v * 0.70710678118654752f));
                    ((unsigned short*)Cout)[(size_t)row*ldc + col] = f2bf(v);
                } else {
                    v += bias[col] + resid[(size_t)row*ldc + col];
                    ((float*)Cout)[(size_t)row*ldc + col] = v;
                }
            }
        }
    }
}

// ---------------- k2: x2 = sum_blk O_blk @ Y_blk + bias0 + rsA*ce + x; fused LN2 ----------------
__launch_bounds__(256)
__global__ void k2_apply(const unsigned short* __restrict__ Y, const float* __restrict__ Og,
                         const float* __restrict__ rsA, const float* __restrict__ bias0,
                         const float* __restrict__ ce, const float* __restrict__ x,
                         const float* __restrict__ n2g, const float* __restrict__ n2b,
                         float* __restrict__ x2, unsigned short* __restrict__ x2n)
{
    __shared__ unsigned short sY[16*1536];
    __shared__ float sO[1536];
    __shared__ float sX[16][257];
    int bb = blockIdx.x, tid = threadIdx.x;

    #pragma unroll
    for (int i = 0; i < 12; ++i) {
        int idx = i*256 + tid;
        *(uint4*)&sY[idx*8] = *(const uint4*)(Y + (size_t)bb*16*1536 + (size_t)idx*8);
    }
    #pragma unroll
    for (int i = 0; i < 6; ++i) sO[i*256 + tid] = Og[(size_t)bb*1536 + i*256 + tid];
    __syncthreads();

    int o = tid;
    float acc[16];
    #pragma unroll
    for (int k = 0; k < 16; ++k) acc[k] = 0.f;
    for (int blk = 0; blk < 6; ++blk) {
        #pragma unroll
        for (int l = 0; l < 16; ++l) {
            float y = bf2f(sY[l*1536 + blk*256 + o]);
            #pragma unroll
            for (int k = 0; k < 16; ++k) acc[k] += sO[blk*256 + k*16 + l] * y;
        }
    }
    float b0 = bias0[o], c0 = ce[o], c1 = ce[256+o], c2 = ce[512+o];
    #pragma unroll
    for (int k = 0; k < 16; ++k) {
        float v = acc[k] + b0
                + rsA[bb*48 +      k] * c0
                + rsA[bb*48 + 16 + k] * c1
                + rsA[bb*48 + 32 + k] * c2
                + x[((size_t)bb*16 + k)*256 + o];
        sX[k][o] = v;
        x2[((size_t)bb*16 + k)*256 + o] = v;
    }
    __syncthreads();

    int r = tid >> 4, g = tid & 15;
    float vv[16]; float sum = 0.f, ss = 0.f;
    #pragma unroll
    for (int m = 0; m < 16; ++m) { float t = sX[r][g*16 + m]; vv[m] = t; sum += t; ss += t*t; }
    #pragma unroll
    for (int off = 8; off; off >>= 1) { sum += __shfl_xor(sum, off); ss += __shfl_xor(ss, off); }
    float mean = sum * (1.f/256.f);
    float rstd = rsqrtf(ss*(1.f/256.f) - mean*mean + LNEPS);
    #pragma unroll
    for (int m = 0; m < 16; ++m) {
        int c = g*16 + m;
        x2n[((size_t)bb*16 + r)*256 + c] = f2bf((vv[m]-mean)*rstd*n2g[c] + n2b[c]);
    }
}

extern "C" void kernel_launch(void* const* d_in, const int* in_sizes, int n_in,
                              void* d_out, int out_size, void* d_ws, size_t ws_size,
                              hipStream_t stream)
{
    (void)in_sizes; (void)n_in; (void)out_size;
    const float* x      = (const float*)d_in[0];
    const float* mask   = (const float*)d_in[1];
    const float* B1g    = (const float*)d_in[2];
    const float* B2g    = (const float*)d_in[3];
    const float* absB1  = (const float*)d_in[4];
    const int*   e_i    = (const int*)d_in[5];
    const int*   e_j    = (const int*)d_in[6];
    const int*   t_ij   = (const int*)d_in[7];
    const int*   t_jk   = (const int*)d_in[8];
    const int*   t_ik   = (const int*)d_in[9];
    const float* geom_w = (const float*)d_in[10];
    const float* geom_b = (const float*)d_in[11];
    const float* log_sc = (const float*)d_in[12];
    const float* wv0_w  = (const float*)d_in[13];
    const float* wv0_b  = (const float*)d_in[14];
    const float* wein_w = (const float*)d_in[15];
    const float* wein_b = (const float*)d_in[16];
    const float* out_w  = (const float*)d_in[17];
    const float* out_b  = (const float*)d_in[18];
    const float* n1_g   = (const float*)d_in[19];
    const float* n1_b   = (const float*)d_in[20];
    const float* n2_g   = (const float*)d_in[21];
    const float* n2_b   = (const float*)d_in[22];
    const float* ffn1_w = (const float*)d_in[23];
    const float* ffn1_b = (const float*)d_in[24];
    const float* ffn2_w = (const float*)d_in[25];
    const float* ffn2_b = (const float*)d_in[26];

    float* out = (float*)d_out;
    float* ws  = (float*)d_ws;
    if (ws_size < (size_t)WS_FLOATS * sizeof(float)) return;

    float* Og    = ws + O_OFF;
    float* rsA   = ws + RSA_OFF;
    float* ce    = ws + CE_OFF;
    float* bias0 = ws + B0_OFF;
    float* C0    = ws + C0_OFF;
    float* C1    = ws + C1_OFF;
    float* U     = ws + U_OFF;
    float* sg    = ws + SG_OFF;
    float* r1    = ws + R1_OFF;
    float* r2    = ws + R2_OFF;
    float* x2    = ws + X2_OFF;
    uint4* ufrag  = (uint4*)(ws + UF_OFF);
    uint4* b1frag = (uint4*)(ws + B1F_OFF);
    unsigned short* wvb   = (unsigned short*)(ws + WVB_OFF);
    unsigned short* weinb = (unsigned short*)(ws + WEB_OFF);
    unsigned short* owTB  = (unsigned short*)(ws + OWT_OFF);
    unsigned short* Qt  = (unsigned short*)(ws + QT_OFF);
    unsigned short* w1t = (unsigned short*)(ws + W1T_OFF);
    unsigned short* w2t = (unsigned short*)(ws + W2T_OFF);
    unsigned short* xnb = (unsigned short*)(ws + XNB_OFF);
    unsigned short* x2n = (unsigned short*)(ws + X2N_OFF);
    unsigned short* Yb  = (unsigned short*)(ws + Y_OFF);
    unsigned short* hb  = (unsigned short*)(ws + H_OFF);

    wprep_k<<<1128, 256, 0, stream>>>(wv0_w, wein_w, out_w, ffn1_w, ffn2_w,
                                      wv0_b, wein_b, out_b, B1g, absB1, B2g,
                                      wvb, weinb, owTB, w1t, w2t,
                                      ce, bias0, C0, C1, U, sg, r1, r2);
    p0b_k<<<22, 64, 0, stream>>>(B1g, U, C0, ufrag, b1frag);
    q_mfma_k<<<dim3(4, 24), 256, 0, stream>>>(owTB, wvb, weinb, Qt);
    k1_build<<<256, 256, 0, stream>>>(x, mask, e_i, e_j, t_ij, t_jk, t_ik,
                                      geom_w, geom_b, log_sc, n1_g, n1_b,
                                      C0, C1, U, sg, r1, r2, ufrag, b1frag,
                                      Og, rsA, xnb);
    // Y = xnb @ Qt^T   (4096x1536, K=256) -> bf16
    gemm_mfma<64, 0><<<dim3(24, 64), 256, 0, stream>>>(xnb, 256, Qt, 256, 4,
                                                       nullptr, nullptr, Yb, 1536);
    k2_apply<<<256, 256, 0, stream>>>(Yb, Og, rsA, bias0, ce, x, n2_g, n2_b, x2, x2n);
    // h = gelu(x2n @ w1t^T + ffn1_b)   (4096x1024, K=256) -> bf16
    gemm_mfma<64, 1><<<dim3(16, 64), 256, 0, stream>>>(x2n, 256, w1t, 256, 4,
                                                       ffn1_b, nullptr, hb, 1024);
    // out = x2 + h @ w2t^T + ffn2_b    (4096x256, K=1024) -> f32
    gemm_mfma<32, 2><<<dim3(4, 128), 256, 0, stream>>>(hb, 1024, w2t, 1024, 16,
                                                       ffn2_b, x2, out, 256);
}

// Round 4
// 149.746 us; speedup vs baseline: 2.1785x; 1.0248x over previous
//
#include <hip/hip_runtime.h>
#include <math.h>

#define TAUF  1.0e-4f
#define LNEPS 1.0e-5f

typedef __bf16 bf16x8 __attribute__((ext_vector_type(8)));
typedef float  f32x4  __attribute__((ext_vector_type(4)));

union U4 { uint4 u4; unsigned short us[8]; bf16x8 bv; };

static __device__ __forceinline__ unsigned short f2bf(float f) {
    union { float f; unsigned u; } v; v.f = f;
    unsigned r = v.u + 0x7fffu + ((v.u >> 16) & 1u);
    return (unsigned short)(r >> 16);
}
static __device__ __forceinline__ float bf2f(unsigned short h) {
    union { unsigned u; float f; } v; v.u = ((unsigned)h) << 16;
    return v.f;
}

// ---------------- workspace layout (float offsets, all 16B-aligned) ----------------
static const unsigned CE_OFF   = 0u;         // 3*256                  -> 768
static const unsigned B0_OFF   = 768u;       // 256                    -> 1024
static const unsigned C0_OFF   = 1024u;      // 256                    -> 1280
static const unsigned C1_OFF   = 1280u;      // 256                    -> 1536
static const unsigned U_OFF    = 1536u;      // 16*560                 -> 10496
static const unsigned SG_OFF   = 10496u;     // 560                    -> 11056
static const unsigned R1_OFF   = 11056u;     // 16                     -> 11072
static const unsigned R2_OFF   = 11072u;     // 16                     -> 11088
static const unsigned UF_OFF   = 11088u;     // 18*64 uint4 (4608 f)   -> 15696
static const unsigned B1F_OFF  = 15696u;     // 4*64 uint4  (1024 f)   -> 16720
static const unsigned WVB_OFF  = 16720u;     // 196608 bf16 (98304 f)  -> 115024
static const unsigned WEB_OFF  = 115024u;    // 196608 bf16 (98304 f)  -> 213328
static const unsigned OWT_OFF  = 213328u;    // 393216 bf16 (196608 f) -> 409936
static const unsigned QT_OFF   = 409936u;    // 393216 bf16 (196608 f) -> 606544
static const unsigned W1T_OFF  = 606544u;    // 262144 bf16 (131072 f) -> 737616
static const unsigned W2T_OFF  = 737616u;    // 262144 bf16 (131072 f) -> 868688
static const unsigned X2_OFF   = 868688u;    // 4096*256 f32           -> 1917264
static const unsigned X2N_OFF  = 1917264u;   // 1048576 bf16 (524288f) -> 2441552
static const unsigned H_OFF    = 2441552u;   // 4194304 bf16 (2097152) -> 4538704
static const unsigned WS_FLOATS = 4538704u;  // ~18.2 MB

// ================= wprep: ALL x-independent prep in ONE launch =================
// b <   96 : f32->bf16 convert wv0_w -> wvb
// b <  192 : f32->bf16 convert wein_w -> weinb
// b <  576 : per-blk transpose out_w -> owTB bf16   (6 x 256x256)
// b <  832 : transpose ffn1_w [256][1024] -> w1t [1024][256] bf16
// b < 1088 : transpose ffn2_w [1024][256] -> w2t [256][1024] bf16
// b < 1092 : bias folds (ce, bias0)
// b < 1128 : complex constants (C0,C1,r1,r2,sigma,U)
// b < 1150 : MFMA operand fragments ufrag (18) / b1frag (4), computed from raw inputs
__launch_bounds__(256)
__global__ void wprep_k(const float* __restrict__ wv0_w, const float* __restrict__ wein_w,
                        const float* __restrict__ out_w,
                        const float* __restrict__ ffn1_w, const float* __restrict__ ffn2_w,
                        const float* __restrict__ wv0_b, const float* __restrict__ wein_b,
                        const float* __restrict__ out_b,
                        const float* __restrict__ B1g, const float* __restrict__ absB1,
                        const float* __restrict__ B2g,
                        unsigned short* __restrict__ wvb, unsigned short* __restrict__ weinb,
                        unsigned short* __restrict__ owTB,
                        unsigned short* __restrict__ w1t, unsigned short* __restrict__ w2t,
                        float* __restrict__ ce, float* __restrict__ bias0,
                        float* __restrict__ C0, float* __restrict__ C1,
                        float* __restrict__ U, float* __restrict__ sigma,
                        float* __restrict__ r1, float* __restrict__ r2,
                        uint4* __restrict__ ufrag, uint4* __restrict__ b1frag)
{
    __shared__ float tile[32][33];
    int b = blockIdx.x, tid = threadIdx.x;
    if (b < 192) {
        const float* src = (b < 96) ? wv0_w : wein_w;
        unsigned short* dst = (b < 96) ? wvb : weinb;
        int base = ((b % 96) * 256 + tid) * 8;
        float4 a = *(const float4*)(src + base);
        float4 c = *(const float4*)(src + base + 4);
        U4 o;
        o.us[0]=f2bf(a.x); o.us[1]=f2bf(a.y); o.us[2]=f2bf(a.z); o.us[3]=f2bf(a.w);
        o.us[4]=f2bf(c.x); o.us[5]=f2bf(c.y); o.us[6]=f2bf(c.z); o.us[7]=f2bf(c.w);
        *(uint4*)(dst + base) = o.u4;
    } else if (b < 576) {
        int bi = b - 192;
        int z = bi >> 6; bi &= 63;
        int r0 = (bi >> 3) * 32, c0 = (bi & 7) * 32;
        int tx = tid & 31, ty = tid >> 5;
        #pragma unroll
        for (int i = 0; i < 4; ++i)
            tile[ty + i*8][tx] = out_w[(size_t)(z*256 + r0 + ty + i*8)*256 + c0 + tx];
        __syncthreads();
        #pragma unroll
        for (int i = 0; i < 4; ++i)
            owTB[(size_t)(z*256 + c0 + ty + i*8)*256 + r0 + tx] = f2bf(tile[tx][ty + i*8]);
    } else if (b < 832) {
        int bi = b - 576;
        int c0 = (bi & 31) * 32, r0 = (bi >> 5) * 32;
        int tx = tid & 31, ty = tid >> 5;
        #pragma unroll
        for (int i = 0; i < 4; ++i)
            tile[ty + i*8][tx] = ffn1_w[(size_t)(r0 + ty + i*8)*1024 + c0 + tx];
        __syncthreads();
        #pragma unroll
        for (int i = 0; i < 4; ++i)
            w1t[(size_t)(c0 + ty + i*8)*256 + r0 + tx] = f2bf(tile[tx][ty + i*8]);
    } else if (b < 1088) {
        int bi = b - 832;
        int c0 = (bi & 7) * 32, r0 = (bi >> 3) * 32;
        int tx = tid & 31, ty = tid >> 5;
        #pragma unroll
        for (int i = 0; i < 4; ++i)
            tile[ty + i*8][tx] = ffn2_w[(size_t)(r0 + ty + i*8)*256 + c0 + tx];
        __syncthreads();
        #pragma unroll
        for (int i = 0; i < 4; ++i)
            w2t[(size_t)(c0 + ty + i*8)*1024 + r0 + tx] = f2bf(tile[tx][ty + i*8]);
    } else if (b < 1092) {
        int which = b - 1088;
        int o = tid;
        if (which == 3) {
            float acc = 0.f;
            for (int r = 0; r < 768; ++r) acc += wv0_b[r] * out_w[(size_t)r*256 + o];
            bias0[o] = out_b[o] + TAUF * acc;
        } else {
            float a2 = 0.f;
            for (int c = 0; c < 256; ++c)
                a2 += wein_b[which*256 + c] * out_w[(size_t)(768 + which*256 + c)*256 + o];
            ce[which*256 + o] = a2;
        }
    } else if (b < 1128) {
        int sub = b - 1092;
        if (sub == 0) {
            int p = tid >> 4, q = tid & 15;
            float c0 = 0.f, c1 = 0.f;
            for (int e = 0; e < 120; ++e) {
                float ap = absB1[p*120+e];
                c0 += ap * B1g[q*120+e];
                c1 += ap * absB1[q*120+e];
            }
            C0[tid] = c0; C1[tid] = c1;
            if (tid < 16) {
                float a = 0.f, bb = 0.f;
                for (int e = 0; e < 120; ++e) { a += B1g[tid*120+e]; bb += absB1[tid*120+e]; }
                r1[tid] = a; r2[tid] = bb;
            }
            for (int t = tid; t < 560; t += 256) {
                float s = 0.f;
                for (int e = 0; e < 120; ++e) s += B2g[e*560+t];
                sigma[t] = s;
            }
        } else {
            int idx = (sub - 1) * 256 + tid;      // 0..8959 over 35 blocks
            int p = idx / 560, t = idx % 560;
            float u = 0.f;
            for (int e = 0; e < 120; ++e) u += absB1[p*120+e] * B2g[e*560+t];
            U[idx] = u;
        }
    } else {
        // MFMA fragments, computed straight from raw inputs (no dependence on U/C0 blocks)
        if (tid < 64) {
            int lane = tid, col = lane & 15, kq = lane >> 4;
            int fb = b - 1128;
            U4 o;
            if (fb < 18) {
                int kt = fb;
                #pragma unroll
                for (int j = 0; j < 8; ++j) {
                    int t = kt*32 + kq*8 + j;
                    float v = 0.f;
                    if (t < 560) {
                        for (int e = 0; e < 120; ++e) v += absB1[col*120+e] * B2g[e*560+t];
                    } else {
                        int p = t - 560;
                        for (int e = 0; e < 120; ++e) v += absB1[col*120+e] * B1g[p*120+e];
                    }
                    o.us[j] = f2bf(v);
                }
                ufrag[kt*64 + lane] = o.u4;
            } else {
                int kt = fb - 18;
                #pragma unroll
                for (int j = 0; j < 8; ++j) {
                    int e = kt*32 + kq*8 + j;
                    o.us[j] = f2bf((e < 120) ? B1g[col*120 + e] : 0.f);
                }
                b1frag[kt*64 + lane] = o.u4;
            }
        }
    }
}

// ============== q_mfma: Qt[blk*256+o][c] = sum_d' out_w[blk*256+d'][o] * Wsel[c][s*256+d'] ==============
__launch_bounds__(256)
__global__ void q_mfma_k(const unsigned short* __restrict__ owTB,
                         const unsigned short* __restrict__ wvb,
                         const unsigned short* __restrict__ weinb,
                         unsigned short* __restrict__ Qt)
{
    __shared__ unsigned short sA[2][64*64];
    __shared__ unsigned short sB[2][64*64];
    const int tid = threadIdx.x;
    const int row0 = blockIdx.y * 64, col0 = blockIdx.x * 64;
    const int blk = row0 >> 8;
    const int s = (blk < 3) ? blk : blk - 3;
    const unsigned short* A  = owTB;                               // lda 256
    const unsigned short* Bt = ((blk < 3) ? wvb : weinb) + s*256;  // ldb 768
    const int lane = tid & 63, w = tid >> 6;
    const int wr = w >> 1, wc = w & 1;
    const int rr = lane & 15, kq = lane >> 4;
    const int lrow = tid >> 3, lkg = tid & 7;

    f32x4 acc[2][2];
    #pragma unroll
    for (int i = 0; i < 2; ++i) { acc[i][0] = 0.0f; acc[i][1] = 0.0f; }

    uint4 ra[2], rb[2];
    auto loadAB = [&](int kt) {
        size_t abase = (size_t)(row0 + lrow)*256 + kt*64 + lkg*8;
        ra[0] = *(const uint4*)(A + abase);
        ra[1] = *(const uint4*)(A + abase + (size_t)32*256);
        size_t bbase = (size_t)(col0 + lrow)*768 + kt*64 + lkg*8;
        rb[0] = *(const uint4*)(Bt + bbase);
        rb[1] = *(const uint4*)(Bt + bbase + (size_t)32*768);
    };
    auto store = [&](int buf) {
        int swz = (lkg ^ (lrow & 7)) * 8;
        *(uint4*)&sA[buf][lrow*64 + swz] = ra[0];
        *(uint4*)&sA[buf][(lrow+32)*64 + swz] = ra[1];
        *(uint4*)&sB[buf][lrow*64 + swz] = rb[0];
        *(uint4*)&sB[buf][(lrow+32)*64 + swz] = rb[1];
    };

    loadAB(0); store(0); __syncthreads();
    for (int kt = 0; kt < 4; ++kt) {
        int cur = kt & 1;
        bool more = (kt + 1 < 4);
        if (more) loadAB(kt + 1);
        #pragma unroll
        for (int ks = 0; ks < 2; ++ks) {
            bf16x8 af[2], bfv[2];
            #pragma unroll
            for (int i = 0; i < 2; ++i) {
                int row = wr*32 + i*16 + rr;
                int kg = ks*4 + kq;
                af[i] = *(const bf16x8*)&sA[cur][row*64 + ((kg ^ (row & 7))*8)];
            }
            #pragma unroll
            for (int j = 0; j < 2; ++j) {
                int n = wc*32 + j*16 + rr;
                int kg = ks*4 + kq;
                bfv[j] = *(const bf16x8*)&sB[cur][n*64 + ((kg ^ (n & 7))*8)];
            }
            #pragma unroll
            for (int i = 0; i < 2; ++i)
                #pragma unroll
                for (int j = 0; j < 2; ++j)
                    acc[i][j] = __builtin_amdgcn_mfma_f32_16x16x32_bf16(af[i], bfv[j], acc[i][j], 0, 0, 0);
        }
        __syncthreads();
        if (more) { store(cur ^ 1); __syncthreads(); }
    }
    #pragma unroll
    for (int i = 0; i < 2; ++i)
        #pragma unroll
        for (int j = 0; j < 2; ++j)
            #pragma unroll
            for (int e = 0; e < 4; ++e) {
                int row = row0 + wr*32 + i*16 + kq*4 + e;
                int col = col0 + wc*32 + j*16 + rr;
                Qt[(size_t)row*256 + col] = f2bf(acc[i][j][e]);
            }
}

// ============== k_mid: per-batch LN1 -> P -> W1/W2 -> O(MFMA) -> Y(MFMA) -> x2 -> LN2, fully fused ==============
__launch_bounds__(256)
__global__ void k_mid(const float* __restrict__ x, const float* __restrict__ mask,
                      const int* __restrict__ e_i, const int* __restrict__ e_j,
                      const int* __restrict__ t_ij, const int* __restrict__ t_jk,
                      const int* __restrict__ t_ik,
                      const float* __restrict__ geom_w, const float* __restrict__ geom_b,
                      const float* __restrict__ log_sc,
                      const float* __restrict__ n1_g, const float* __restrict__ n1_b,
                      const float* __restrict__ n2g, const float* __restrict__ n2b,
                      const float* __restrict__ C0, const float* __restrict__ C1,
                      const float* __restrict__ Up, const float* __restrict__ sg,
                      const float* __restrict__ r1, const float* __restrict__ r2,
                      const uint4* __restrict__ ufrag, const uint4* __restrict__ b1frag,
                      const unsigned short* __restrict__ Qt,
                      const float* __restrict__ bias0, const float* __restrict__ ce,
                      float* __restrict__ x2, unsigned short* __restrict__ x2n)
{
    __shared__ float sxn[16][257];            // f32 xn (for P)
    __shared__ unsigned short sxnB[16*256];   // bf16 xn, XOR-swizzled chunks (A-frags)
    __shared__ float sP[16][17];
    __shared__ float sW1e[3][128];
    __shared__ float sW2e[3][576];
    __shared__ float sSig[560];
    __shared__ float sMask[16];
    __shared__ float sO[6*256];               // six 16x16 operators
    __shared__ float sRs[240];
    __shared__ float sRsA[48];
    __shared__ unsigned short sY[16*1544];    // Y tile, padded rows
    __shared__ float sX[16][257];             // x2 rows (for LN2)

    int bb = blockIdx.x, tid = threadIdx.x;
    int r = tid >> 4, g = tid & 15;

    // ---- LayerNorm 1 -> sxn (f32) + sxnB (bf16, swizzled) ----
    {
        const float* row = x + ((size_t)bb*16 + r)*256;
        float v[16]; float sum = 0.f, ss = 0.f;
        #pragma unroll
        for (int m = 0; m < 16; ++m) { float t = row[g*16 + m]; v[m] = t; sum += t; ss += t*t; }
        #pragma unroll
        for (int o = 8; o; o >>= 1) { sum += __shfl_xor(sum, o); ss += __shfl_xor(ss, o); }
        float mean = sum * (1.f/256.f);
        float rstd = rsqrtf(ss*(1.f/256.f) - mean*mean + LNEPS);
        #pragma unroll
        for (int m = 0; m < 16; ++m) {
            int c = g*16 + m;
            float xv = (v[m]-mean)*rstd*n1_g[c] + n1_b[c];
            sxn[r][c] = xv;
            v[m] = xv;
        }
        #pragma unroll
        for (int h = 0; h < 2; ++h) {
            int kg = g*2 + h;                                   // 16B chunk index 0..31
            int swz = (kg & 24) | ((kg & 7) ^ (r & 7));
            U4 o;
            #pragma unroll
            for (int j = 0; j < 8; ++j) o.us[j] = f2bf(v[h*8 + j]);
            *(uint4*)&sxnB[r*256 + swz*8] = o.u4;
        }
        if (tid < 16) sMask[tid] = mask[bb*16 + tid];
    }
    for (int i = tid; i < 560; i += 256) sSig[i] = sg[i];
    __syncthreads();

    // ---- P = xn @ geom_w + geom_b ----
    {
        float a0 = 0.f, a1 = 0.f, a2 = 0.f, a3 = 0.f;
        for (int c = 0; c < 256; c += 4) {
            a0 += sxn[r][c+0] * geom_w[(c+0)*16 + g];
            a1 += sxn[r][c+1] * geom_w[(c+1)*16 + g];
            a2 += sxn[r][c+2] * geom_w[(c+2)*16 + g];
            a3 += sxn[r][c+3] * geom_w[(c+3)*16 + g];
        }
        sP[r][g] = (a0+a1) + (a2+a3) + geom_b[g];
    }
    __syncthreads();

    // ---- W1 (3x120) + zero-pad to 128 ----
    if (tid < 128) {
        if (tid < 120) {
            int e = tid, i0 = e_i[e], j0 = e_j[e];
            float d2 = 0.f;
            #pragma unroll
            for (int m = 0; m < 16; ++m) { float dd = sP[i0][m] - sP[j0][m]; d2 += dd*dd; }
            float mm = sMask[i0]*sMask[j0];
            d2 *= mm*mm;
            #pragma unroll
            for (int s = 0; s < 3; ++s) {
                float sc = expf(log_sc[s]);
                sW1e[s][e] = expf(-d2/(2.f*sc*sc + 1e-8f)) * mm;
            }
        } else {
            #pragma unroll
            for (int s = 0; s < 3; ++s) sW1e[s][tid] = 0.f;
        }
    }
    __syncthreads();

    // ---- W2 (3x560) + mask extension (t 560..575) ----
    for (int t = tid; t < 560; t += 256) {
        int a = t_ij[t], b2 = t_jk[t], c2 = t_ik[t];
        #pragma unroll
        for (int s = 0; s < 3; ++s) sW2e[s][t] = sW1e[s][a]*sW1e[s][b2]*sW1e[s][c2];
    }
    if (tid < 48) {
        int s = tid >> 4, p = tid & 15;
        sW2e[s][560 + p] = sMask[p];
    }
    __syncthreads();

    // ---- MFMA operator build -> sO; rsA partials -> sRs ----
    int lane = tid & 63, w = tid >> 6;
    int rr = lane & 15, kq = lane >> 4;
    if (w < 3) {
        int s = w;
        f32x4 acc = {0.f, 0.f, 0.f, 0.f};
        for (int kt = 0; kt < 18; ++kt) {
            U4 ub; ub.u4 = ufrag[kt*64 + lane];
            const float4* w4 = (const float4*)&sW2e[s][kt*32 + kq*8];
            float4 wa = w4[0], wb = w4[1];
            U4 av;
            av.us[0] = f2bf(wa.x * bf2f(ub.us[0]));
            av.us[1] = f2bf(wa.y * bf2f(ub.us[1]));
            av.us[2] = f2bf(wa.z * bf2f(ub.us[2]));
            av.us[3] = f2bf(wa.w * bf2f(ub.us[3]));
            av.us[4] = f2bf(wb.x * bf2f(ub.us[4]));
            av.us[5] = f2bf(wb.y * bf2f(ub.us[5]));
            av.us[6] = f2bf(wb.z * bf2f(ub.us[6]));
            av.us[7] = f2bf(wb.w * bf2f(ub.us[7]));
            acc = __builtin_amdgcn_mfma_f32_16x16x32_bf16(av.bv, ub.bv, acc, 0, 0, 0);
        }
        #pragma unroll
        for (int e = 0; e < 4; ++e) {
            int row = kq*4 + e;
            sO[(3+s)*256 + row*16 + rr] = acc[e] + TAUF*C1[row*16 + rr];
        }
    } else {
        f32x4 acc3[3];
        acc3[0] = 0.f; acc3[1] = 0.f; acc3[2] = 0.f;
        for (int kt = 0; kt < 4; ++kt) {
            U4 ub; ub.u4 = b1frag[kt*64 + lane];
            float uf[8];
            #pragma unroll
            for (int j = 0; j < 8; ++j) uf[j] = bf2f(ub.us[j]);
            #pragma unroll
            for (int s = 0; s < 3; ++s) {
                const float4* w4 = (const float4*)&sW1e[s][kt*32 + kq*8];
                float4 wa = w4[0], wb = w4[1];
                U4 av;
                av.us[0] = f2bf(wa.x * uf[0]);
                av.us[1] = f2bf(wa.y * uf[1]);
                av.us[2] = f2bf(wa.z * uf[2]);
                av.us[3] = f2bf(wa.w * uf[3]);
                av.us[4] = f2bf(wb.x * uf[4]);
                av.us[5] = f2bf(wb.y * uf[5]);
                av.us[6] = f2bf(wb.z * uf[6]);
                av.us[7] = f2bf(wb.w * uf[7]);
                acc3[s] = __builtin_amdgcn_mfma_f32_16x16x32_bf16(av.bv, ub.bv, acc3[s], 0, 0, 0);
            }
        }
        #pragma unroll
        for (int s = 0; s < 3; ++s)
            #pragma unroll
            for (int e = 0; e < 4; ++e) {
                int row = kq*4 + e;
                sO[s*256 + row*16 + rr] = acc3[s][e] + ((row == rr) ? TAUF : 0.f);
            }
    }
    if (tid < 240) {
        int s = tid / 80, rem = tid % 80;
        int k = rem / 5, ch = rem % 5;
        float p = 0.f;
        int t0 = ch * 112;
        for (int i = 0; i < 112; ++i) {
            int t = t0 + i;
            p += sW2e[s][t] * sSig[t] * Up[k*560 + t];
        }
        sRs[(s*16 + k)*5 + ch] = p;
    }
    __syncthreads();

    // ---- rsA combine (tid<48) + Y-GEMM: Y[l][n] = sum_c xn[l][c]*Qt[n][c], B-frags from global ----
    if (tid < 48) {
        int k = tid & 15;
        float a = TAUF * r2[k];
        #pragma unroll
        for (int p = 0; p < 16; ++p) a += C0[k*16 + p] * sMask[p] * r1[p];
        #pragma unroll
        for (int ch = 0; ch < 5; ++ch) a += sRs[tid*5 + ch];
        sRsA[tid] = a;
    }
    // wave w handles n16-tiles [w*24, w*24+24), 4 concurrent tiles per group
    for (int grp = 0; grp < 6; ++grp) {
        int nt0 = w*24 + grp*4;
        f32x4 acc0 = {0.f,0.f,0.f,0.f}, acc1 = acc0, acc2 = acc0, acc3 = acc0;
        #pragma unroll
        for (int kt = 0; kt < 8; ++kt) {
            int kg = kt*4 + kq;
            int swz = (kg & 24) | ((kg & 7) ^ (rr & 7));
            bf16x8 af = *(const bf16x8*)&sxnB[rr*256 + swz*8];
            U4 b0, b1, b2, b3;
            b0.u4 = *(const uint4*)(Qt + (size_t)((nt0+0)*16 + rr)*256 + kt*32 + kq*8);
            b1.u4 = *(const uint4*)(Qt + (size_t)((nt0+1)*16 + rr)*256 + kt*32 + kq*8);
            b2.u4 = *(const uint4*)(Qt + (size_t)((nt0+2)*16 + rr)*256 + kt*32 + kq*8);
            b3.u4 = *(const uint4*)(Qt + (size_t)((nt0+3)*16 + rr)*256 + kt*32 + kq*8);
            acc0 = __builtin_amdgcn_mfma_f32_16x16x32_bf16(af, b0.bv, acc0, 0, 0, 0);
            acc1 = __builtin_amdgcn_mfma_f32_16x16x32_bf16(af, b1.bv, acc1, 0, 0, 0);
            acc2 = __builtin_amdgcn_mfma_f32_16x16x32_bf16(af, b2.bv, acc2, 0, 0, 0);
            acc3 = __builtin_amdgcn_mfma_f32_16x16x32_bf16(af, b3.bv, acc3, 0, 0, 0);
        }
        #pragma unroll
        for (int e = 0; e < 4; ++e) {
            int l = kq*4 + e;
            sY[l*1544 + (nt0+0)*16 + rr] = f2bf(acc0[e]);
            sY[l*1544 + (nt0+1)*16 + rr] = f2bf(acc1[e]);
            sY[l*1544 + (nt0+2)*16 + rr] = f2bf(acc2[e]);
            sY[l*1544 + (nt0+3)*16 + rr] = f2bf(acc3[e]);
        }
    }
    __syncthreads();

    // ---- O-contraction + epilogue -> sX, x2 ----
    {
        int o = tid;
        float acc[16];
        #pragma unroll
        for (int k = 0; k < 16; ++k) acc[k] = 0.f;
        #pragma unroll
        for (int blk = 0; blk < 6; ++blk) {
            #pragma unroll
            for (int l = 0; l < 16; ++l) {
                float y = bf2f(sY[l*1544 + blk*256 + o]);
                #pragma unroll
                for (int k = 0; k < 16; ++k) acc[k] += sO[blk*256 + k*16 + l] * y;
            }
        }
        float b0 = bias0[o], c0 = ce[o], c1 = ce[256+o], c2 = ce[512+o];
        #pragma unroll
        for (int k = 0; k < 16; ++k) {
            float v = acc[k] + b0
                    + sRsA[     k] * c0
                    + sRsA[16 + k] * c1
                    + sRsA[32 + k] * c2
                    + x[((size_t)bb*16 + k)*256 + o];
            sX[k][o] = v;
            x2[((size_t)bb*16 + k)*256 + o] = v;
        }
    }
    __syncthreads();

    // ---- LN2 -> x2n (bf16) ----
    {
        float vv[16]; float sum = 0.f, ss = 0.f;
        #pragma unroll
        for (int m = 0; m < 16; ++m) { float t = sX[r][g*16 + m]; vv[m] = t; sum += t; ss += t*t; }
        #pragma unroll
        for (int off = 8; off; off >>= 1) { sum += __shfl_xor(sum, off); ss += __shfl_xor(ss, off); }
        float mean = sum * (1.f/256.f);
        float rstd = rsqrtf(ss*(1.f/256.f) - mean*mean + LNEPS);
        #pragma unroll
        for (int m = 0; m < 16; ++m) {
            int c = g*16 + m;
            x2n[((size_t)bb*16 + r)*256 + c] = f2bf((vv[m]-mean)*rstd*n2g[c] + n2b[c]);
        }
    }
}

// ---------------- MFMA bf16 GEMM (FFN1 / FFN2) ----------------
template<int BM, int EPI>
__launch_bounds__(256)
__global__ void gemm_mfma(const unsigned short* __restrict__ A, int lda,
                          const unsigned short* __restrict__ Bt, int ldb,
                          int nk,
                          const float* __restrict__ bias,
                          const float* __restrict__ resid,
                          void* __restrict__ Cout, int ldc)
{
    constexpr int WM = BM/2;
    constexpr int MI = WM/16;
    __shared__ unsigned short sA[2][BM*64];
    __shared__ unsigned short sB[2][64*64];
    const int tid = threadIdx.x;
    const int row0 = blockIdx.y * BM, col0 = blockIdx.x * 64;
    const int lane = tid & 63, w = tid >> 6;
    const int wr = w >> 1, wc = w & 1;
    const int rr = lane & 15, kq = lane >> 4;
    const int lrow = tid >> 3, lkg = tid & 7;

    f32x4 acc[MI][2];
    #pragma unroll
    for (int i = 0; i < MI; ++i) { acc[i][0] = 0.0f; acc[i][1] = 0.0f; }

    uint4 ra[2], rb[2];
    auto loadAB = [&](int kt) {
        size_t abase = (size_t)(row0 + lrow)*lda + kt*64 + lkg*8;
        ra[0] = *(const uint4*)(A + abase);
        if constexpr (BM == 64) ra[1] = *(const uint4*)(A + abase + (size_t)32*lda);
        size_t bbase = (size_t)(col0 + lrow)*ldb + kt*64 + lkg*8;
        rb[0] = *(const uint4*)(Bt + bbase);
        rb[1] = *(const uint4*)(Bt + bbase + (size_t)32*ldb);
    };
    auto store = [&](int buf) {
        int swz = (lkg ^ (lrow & 7)) * 8;
        *(uint4*)&sA[buf][lrow*64 + swz] = ra[0];
        if constexpr (BM == 64) *(uint4*)&sA[buf][(lrow+32)*64 + swz] = ra[1];
        *(uint4*)&sB[buf][lrow*64 + swz] = rb[0];
        *(uint4*)&sB[buf][(lrow+32)*64 + swz] = rb[1];
    };

    loadAB(0); store(0); __syncthreads();

    for (int kt = 0; kt < nk; ++kt) {
        int cur = kt & 1;
        bool more = (kt + 1 < nk);
        if (more) loadAB(kt + 1);
        #pragma unroll
        for (int ks = 0; ks < 2; ++ks) {
            bf16x8 af[MI], bfv[2];
            #pragma unroll
            for (int i = 0; i < MI; ++i) {
                int row = wr*WM + i*16 + rr;
                int kg = ks*4 + kq;
                af[i] = *(const bf16x8*)&sA[cur][row*64 + ((kg ^ (row & 7))*8)];
            }
            #pragma unroll
            for (int j = 0; j < 2; ++j) {
                int n = wc*32 + j*16 + rr;
                int kg = ks*4 + kq;
                bfv[j] = *(const bf16x8*)&sB[cur][n*64 + ((kg ^ (n & 7))*8)];
            }
            #pragma unroll
            for (int i = 0; i < MI; ++i)
                #pragma unroll
                for (int j = 0; j < 2; ++j)
                    acc[i][j] = __builtin_amdgcn_mfma_f32_16x16x32_bf16(af[i], bfv[j], acc[i][j], 0, 0, 0);
        }
        __syncthreads();
        if (more) { store(cur ^ 1); __syncthreads(); }
    }

    #pragma unroll
    for (int i = 0; i < MI; ++i) {
        #pragma unroll
        for (int j = 0; j < 2; ++j) {
            #pragma unroll
            for (int e = 0; e < 4; ++e) {
                int row = row0 + wr*WM + i*16 + kq*4 + e;
                int col = col0 + wc*32 + j*16 + rr;
                float v = acc[i][j][e];
                if (EPI == 1) {
                    v += bias[col];
                    v = 0.5f * v * (1.f + erff(v * 0.70710678118654752f));
                    ((unsigned short*)Cout)[(size_t)row*ldc + col] = f2bf(v);
                } else {
                    v += bias[col] + resid[(size_t)row*ldc + col];
                    ((float*)Cout)[(size_t)row*ldc + col] = v;
                }
            }
        }
    }
}

extern "C" void kernel_launch(void* const* d_in, const int* in_sizes, int n_in,
                              void* d_out, int out_size, void* d_ws, size_t ws_size,
                              hipStream_t stream)
{
    (void)in_sizes; (void)n_in; (void)out_size;
    const float* x      = (const float*)d_in[0];
    const float* mask   = (const float*)d_in[1];
    const float* B1g    = (const float*)d_in[2];
    const float* B2g    = (const float*)d_in[3];
    const float* absB1  = (const float*)d_in[4];
    const int*   e_i    = (const int*)d_in[5];
    const int*   e_j    = (const int*)d_in[6];
    const int*   t_ij   = (const int*)d_in[7];
    const int*   t_jk   = (const int*)d_in[8];
    const int*   t_ik   = (const int*)d_in[9];
    const float* geom_w = (const float*)d_in[10];
    const float* geom_b = (const float*)d_in[11];
    const float* log_sc = (const float*)d_in[12];
    const float* wv0_w  = (const float*)d_in[13];
    const float* wv0_b  = (const float*)d_in[14];
    const float* wein_w = (const float*)d_in[15];
    const float* wein_b = (const float*)d_in[16];
    const float* out_w  = (const float*)d_in[17];
    const float* out_b  = (const float*)d_in[18];
    const float* n1_g   = (const float*)d_in[19];
    const float* n1_b   = (const float*)d_in[20];
    const float* n2_g   = (const float*)d_in[21];
    const float* n2_b   = (const float*)d_in[22];
    const float* ffn1_w = (const float*)d_in[23];
    const float* ffn1_b = (const float*)d_in[24];
    const float* ffn2_w = (const float*)d_in[25];
    const float* ffn2_b = (const float*)d_in[26];

    float* out = (float*)d_out;
    float* ws  = (float*)d_ws;
    if (ws_size < (size_t)WS_FLOATS * sizeof(float)) return;

    float* ce    = ws + CE_OFF;
    float* bias0 = ws + B0_OFF;
    float* C0    = ws + C0_OFF;
    float* C1    = ws + C1_OFF;
    float* U     = ws + U_OFF;
    float* sg    = ws + SG_OFF;
    float* r1    = ws + R1_OFF;
    float* r2    = ws + R2_OFF;
    float* x2    = ws + X2_OFF;
    uint4* ufrag  = (uint4*)(ws + UF_OFF);
    uint4* b1frag = (uint4*)(ws + B1F_OFF);
    unsigned short* wvb   = (unsigned short*)(ws + WVB_OFF);
    unsigned short* weinb = (unsigned short*)(ws + WEB_OFF);
    unsigned short* owTB  = (unsigned short*)(ws + OWT_OFF);
    unsigned short* Qt  = (unsigned short*)(ws + QT_OFF);
    unsigned short* w1t = (unsigned short*)(ws + W1T_OFF);
    unsigned short* w2t = (unsigned short*)(ws + W2T_OFF);
    unsigned short* x2n = (unsigned short*)(ws + X2N_OFF);
    unsigned short* hb  = (unsigned short*)(ws + H_OFF);

    wprep_k<<<1150, 256, 0, stream>>>(wv0_w, wein_w, out_w, ffn1_w, ffn2_w,
                                      wv0_b, wein_b, out_b, B1g, absB1, B2g,
                                      wvb, weinb, owTB, w1t, w2t,
                                      ce, bias0, C0, C1, U, sg, r1, r2,
                                      ufrag, b1frag);
    q_mfma_k<<<dim3(4, 24), 256, 0, stream>>>(owTB, wvb, weinb, Qt);
    k_mid<<<256, 256, 0, stream>>>(x, mask, e_i, e_j, t_ij, t_jk, t_ik,
                                   geom_w, geom_b, log_sc, n1_g, n1_b, n2_g, n2_b,
                                   C0, C1, U, sg, r1, r2, ufrag, b1frag,
                                   Qt, bias0, ce, x2, x2n);
    // h = gelu(x2n @ w1t^T + ffn1_b)   (4096x1024, K=256) -> bf16
    gemm_mfma<64, 1><<<dim3(16, 64), 256, 0, stream>>>(x2n, 256, w1t, 256, 4,
                                                       ffn1_b, nullptr, hb, 1024);
    // out = x2 + h @ w2t^T + ffn2_b    (4096x256, K=1024) -> f32
    gemm_mfma<32, 2><<<dim3(4, 128), 256, 0, stream>>>(hb, 1024, w2t, 1024, 16,
                                                       ffn2_b, x2, out, 256);
}

// Round 5
// 120.349 us; speedup vs baseline: 2.7106x; 1.2443x over previous
//
#include <hip/hip_runtime.h>
#include <math.h>

#define TAUF  1.0e-4f
#define LNEPS 1.0e-5f

typedef __bf16 bf16x8 __attribute__((ext_vector_type(8)));
typedef float  f32x4  __attribute__((ext_vector_type(4)));

union U4 { uint4 u4; unsigned short us[8]; bf16x8 bv; };

static __device__ __forceinline__ unsigned short f2bf(float f) {
    union { float f; unsigned u; } v; v.f = f;
    unsigned r = v.u + 0x7fffu + ((v.u >> 16) & 1u);
    return (unsigned short)(r >> 16);
}
static __device__ __forceinline__ float bf2f(unsigned short h) {
    union { unsigned u; float f; } v; v.u = ((unsigned)h) << 16;
    return v.f;
}

// ---------------- workspace layout (float offsets, all 16B-aligned) ----------------
static const unsigned CE_OFF   = 0u;         // 3*256                  -> 768
static const unsigned B0_OFF   = 768u;       // 256                    -> 1024
static const unsigned C0_OFF   = 1024u;      // 256                    -> 1280
static const unsigned C1_OFF   = 1280u;      // 256                    -> 1536
static const unsigned U_OFF    = 1536u;      // 16*560                 -> 10496
static const unsigned SG_OFF   = 10496u;     // 560                    -> 11056
static const unsigned R1_OFF   = 11056u;     // 16                     -> 11072
static const unsigned R2_OFF   = 11072u;     // 16                     -> 11088
static const unsigned UF_OFF   = 11088u;     // 18*64 uint4 (4608 f)   -> 15696
static const unsigned B1F_OFF  = 15696u;     // 4*64 uint4  (1024 f)   -> 16720
static const unsigned WVB_OFF  = 16720u;     // 196608 bf16 (98304 f)  -> 115024
static const unsigned WEB_OFF  = 115024u;    // 196608 bf16 (98304 f)  -> 213328
static const unsigned OWT_OFF  = 213328u;    // 393216 bf16 (196608 f) -> 409936
static const unsigned QT_OFF   = 409936u;    // 393216 bf16 (196608 f) -> 606544
static const unsigned W1T_OFF  = 606544u;    // 262144 bf16 (131072 f) -> 737616
static const unsigned W2T_OFF  = 737616u;    // 262144 bf16 (131072 f) -> 868688
static const unsigned WS_FLOATS = 868688u;   // ~3.5 MB

// ================= wprep: ALL x-independent prep in ONE launch =================
__launch_bounds__(256)
__global__ void wprep_k(const float* __restrict__ wv0_w, const float* __restrict__ wein_w,
                        const float* __restrict__ out_w,
                        const float* __restrict__ ffn1_w, const float* __restrict__ ffn2_w,
                        const float* __restrict__ wv0_b, const float* __restrict__ wein_b,
                        const float* __restrict__ out_b,
                        const float* __restrict__ B1g, const float* __restrict__ absB1,
                        const float* __restrict__ B2g,
                        unsigned short* __restrict__ wvb, unsigned short* __restrict__ weinb,
                        unsigned short* __restrict__ owTB,
                        unsigned short* __restrict__ w1t, unsigned short* __restrict__ w2t,
                        float* __restrict__ ce, float* __restrict__ bias0,
                        float* __restrict__ C0, float* __restrict__ C1,
                        float* __restrict__ U, float* __restrict__ sigma,
                        float* __restrict__ r1, float* __restrict__ r2,
                        uint4* __restrict__ ufrag, uint4* __restrict__ b1frag)
{
    __shared__ float tile[32][33];
    int b = blockIdx.x, tid = threadIdx.x;
    if (b < 192) {
        const float* src = (b < 96) ? wv0_w : wein_w;
        unsigned short* dst = (b < 96) ? wvb : weinb;
        int base = ((b % 96) * 256 + tid) * 8;
        float4 a = *(const float4*)(src + base);
        float4 c = *(const float4*)(src + base + 4);
        U4 o;
        o.us[0]=f2bf(a.x); o.us[1]=f2bf(a.y); o.us[2]=f2bf(a.z); o.us[3]=f2bf(a.w);
        o.us[4]=f2bf(c.x); o.us[5]=f2bf(c.y); o.us[6]=f2bf(c.z); o.us[7]=f2bf(c.w);
        *(uint4*)(dst + base) = o.u4;
    } else if (b < 576) {
        int bi = b - 192;
        int z = bi >> 6; bi &= 63;
        int r0 = (bi >> 3) * 32, c0 = (bi & 7) * 32;
        int tx = tid & 31, ty = tid >> 5;
        #pragma unroll
        for (int i = 0; i < 4; ++i)
            tile[ty + i*8][tx] = out_w[(size_t)(z*256 + r0 + ty + i*8)*256 + c0 + tx];
        __syncthreads();
        #pragma unroll
        for (int i = 0; i < 4; ++i)
            owTB[(size_t)(z*256 + c0 + ty + i*8)*256 + r0 + tx] = f2bf(tile[tx][ty + i*8]);
    } else if (b < 832) {
        int bi = b - 576;
        int c0 = (bi & 31) * 32, r0 = (bi >> 5) * 32;
        int tx = tid & 31, ty = tid >> 5;
        #pragma unroll
        for (int i = 0; i < 4; ++i)
            tile[ty + i*8][tx] = ffn1_w[(size_t)(r0 + ty + i*8)*1024 + c0 + tx];
        __syncthreads();
        #pragma unroll
        for (int i = 0; i < 4; ++i)
            w1t[(size_t)(c0 + ty + i*8)*256 + r0 + tx] = f2bf(tile[tx][ty + i*8]);
    } else if (b < 1088) {
        int bi = b - 832;
        int c0 = (bi & 7) * 32, r0 = (bi >> 3) * 32;
        int tx = tid & 31, ty = tid >> 5;
        #pragma unroll
        for (int i = 0; i < 4; ++i)
            tile[ty + i*8][tx] = ffn2_w[(size_t)(r0 + ty + i*8)*256 + c0 + tx];
        __syncthreads();
        #pragma unroll
        for (int i = 0; i < 4; ++i)
            w2t[(size_t)(c0 + ty + i*8)*1024 + r0 + tx] = f2bf(tile[tx][ty + i*8]);
    } else if (b < 1092) {
        int which = b - 1088;
        int o = tid;
        if (which == 3) {
            float acc = 0.f;
            for (int r = 0; r < 768; ++r) acc += wv0_b[r] * out_w[(size_t)r*256 + o];
            bias0[o] = out_b[o] + TAUF * acc;
        } else {
            float a2 = 0.f;
            for (int c = 0; c < 256; ++c)
                a2 += wein_b[which*256 + c] * out_w[(size_t)(768 + which*256 + c)*256 + o];
            ce[which*256 + o] = a2;
        }
    } else if (b < 1128) {
        int sub = b - 1092;
        if (sub == 0) {
            int p = tid >> 4, q = tid & 15;
            float c0 = 0.f, c1 = 0.f;
            for (int e = 0; e < 120; ++e) {
                float ap = absB1[p*120+e];
                c0 += ap * B1g[q*120+e];
                c1 += ap * absB1[q*120+e];
            }
            C0[tid] = c0; C1[tid] = c1;
            if (tid < 16) {
                float a = 0.f, bb = 0.f;
                for (int e = 0; e < 120; ++e) { a += B1g[tid*120+e]; bb += absB1[tid*120+e]; }
                r1[tid] = a; r2[tid] = bb;
            }
            for (int t = tid; t < 560; t += 256) {
                float s = 0.f;
                for (int e = 0; e < 120; ++e) s += B2g[e*560+t];
                sigma[t] = s;
            }
        } else {
            int idx = (sub - 1) * 256 + tid;      // 0..8959 over 35 blocks
            int p = idx / 560, t = idx % 560;
            float u = 0.f;
            for (int e = 0; e < 120; ++e) u += absB1[p*120+e] * B2g[e*560+t];
            U[idx] = u;
        }
    } else {
        if (tid < 64) {
            int lane = tid, col = lane & 15, kq = lane >> 4;
            int fb = b - 1128;
            U4 o;
            if (fb < 18) {
                int kt = fb;
                #pragma unroll
                for (int j = 0; j < 8; ++j) {
                    int t = kt*32 + kq*8 + j;
                    float v = 0.f;
                    if (t < 560) {
                        for (int e = 0; e < 120; ++e) v += absB1[col*120+e] * B2g[e*560+t];
                    } else {
                        int p = t - 560;
                        for (int e = 0; e < 120; ++e) v += absB1[col*120+e] * B1g[p*120+e];
                    }
                    o.us[j] = f2bf(v);
                }
                ufrag[kt*64 + lane] = o.u4;
            } else {
                int kt = fb - 18;
                #pragma unroll
                for (int j = 0; j < 8; ++j) {
                    int e = kt*32 + kq*8 + j;
                    o.us[j] = f2bf((e < 120) ? B1g[col*120 + e] : 0.f);
                }
                b1frag[kt*64 + lane] = o.u4;
            }
        }
    }
}

// ============== q_mfma: Qt[blk*256+o][c] (unchanged, passing) ==============
__launch_bounds__(256)
__global__ void q_mfma_k(const unsigned short* __restrict__ owTB,
                         const unsigned short* __restrict__ wvb,
                         const unsigned short* __restrict__ weinb,
                         unsigned short* __restrict__ Qt)
{
    __shared__ unsigned short sA[2][64*64];
    __shared__ unsigned short sB[2][64*64];
    const int tid = threadIdx.x;
    const int row0 = blockIdx.y * 64, col0 = blockIdx.x * 64;
    const int blk = row0 >> 8;
    const int s = (blk < 3) ? blk : blk - 3;
    const unsigned short* A  = owTB;
    const unsigned short* Bt = ((blk < 3) ? wvb : weinb) + s*256;
    const int lane = tid & 63, w = tid >> 6;
    const int wr = w >> 1, wc = w & 1;
    const int rr = lane & 15, kq = lane >> 4;
    const int lrow = tid >> 3, lkg = tid & 7;

    f32x4 acc[2][2];
    #pragma unroll
    for (int i = 0; i < 2; ++i) { acc[i][0] = 0.0f; acc[i][1] = 0.0f; }

    uint4 ra[2], rb[2];
    auto loadAB = [&](int kt) {
        size_t abase = (size_t)(row0 + lrow)*256 + kt*64 + lkg*8;
        ra[0] = *(const uint4*)(A + abase);
        ra[1] = *(const uint4*)(A + abase + (size_t)32*256);
        size_t bbase = (size_t)(col0 + lrow)*768 + kt*64 + lkg*8;
        rb[0] = *(const uint4*)(Bt + bbase);
        rb[1] = *(const uint4*)(Bt + bbase + (size_t)32*768);
    };
    auto store = [&](int buf) {
        int swz = (lkg ^ (lrow & 7)) * 8;
        *(uint4*)&sA[buf][lrow*64 + swz] = ra[0];
        *(uint4*)&sA[buf][(lrow+32)*64 + swz] = ra[1];
        *(uint4*)&sB[buf][lrow*64 + swz] = rb[0];
        *(uint4*)&sB[buf][(lrow+32)*64 + swz] = rb[1];
    };

    loadAB(0); store(0); __syncthreads();
    for (int kt = 0; kt < 4; ++kt) {
        int cur = kt & 1;
        bool more = (kt + 1 < 4);
        if (more) loadAB(kt + 1);
        #pragma unroll
        for (int ks = 0; ks < 2; ++ks) {
            bf16x8 af[2], bfv[2];
            #pragma unroll
            for (int i = 0; i < 2; ++i) {
                int row = wr*32 + i*16 + rr;
                int kg = ks*4 + kq;
                af[i] = *(const bf16x8*)&sA[cur][row*64 + ((kg ^ (row & 7))*8)];
            }
            #pragma unroll
            for (int j = 0; j < 2; ++j) {
                int n = wc*32 + j*16 + rr;
                int kg = ks*4 + kq;
                bfv[j] = *(const bf16x8*)&sB[cur][n*64 + ((kg ^ (n & 7))*8)];
            }
            #pragma unroll
            for (int i = 0; i < 2; ++i)
                #pragma unroll
                for (int j = 0; j < 2; ++j)
                    acc[i][j] = __builtin_amdgcn_mfma_f32_16x16x32_bf16(af[i], bfv[j], acc[i][j], 0, 0, 0);
        }
        __syncthreads();
        if (more) { store(cur ^ 1); __syncthreads(); }
    }
    #pragma unroll
    for (int i = 0; i < 2; ++i)
        #pragma unroll
        for (int j = 0; j < 2; ++j)
            #pragma unroll
            for (int e = 0; e < 4; ++e) {
                int row = row0 + wr*32 + i*16 + kq*4 + e;
                int col = col0 + wc*32 + j*16 + rr;
                Qt[(size_t)row*256 + col] = f2bf(acc[i][j][e]);
            }
}

// ============== k_mega: full per-batch pipeline, 512 threads, nothing leaves LDS but `out` ==============
__launch_bounds__(512)
__global__ void k_mega(const float* __restrict__ x, const float* __restrict__ mask,
                       const int* __restrict__ e_i, const int* __restrict__ e_j,
                       const int* __restrict__ t_ij, const int* __restrict__ t_jk,
                       const int* __restrict__ t_ik,
                       const float* __restrict__ geom_w, const float* __restrict__ geom_b,
                       const float* __restrict__ log_sc,
                       const float* __restrict__ n1_g, const float* __restrict__ n1_b,
                       const float* __restrict__ n2g, const float* __restrict__ n2b,
                       const float* __restrict__ C0, const float* __restrict__ C1,
                       const float* __restrict__ Up, const float* __restrict__ sg,
                       const float* __restrict__ r1, const float* __restrict__ r2,
                       const uint4* __restrict__ ufrag, const uint4* __restrict__ b1frag,
                       const unsigned short* __restrict__ Qt,
                       const float* __restrict__ bias0, const float* __restrict__ ce,
                       const unsigned short* __restrict__ w1t, const float* __restrict__ f1b,
                       const unsigned short* __restrict__ w2t, const float* __restrict__ f2b,
                       float* __restrict__ outp)
{
    __shared__ float sxn[16][257];
    __shared__ unsigned short sxnB[16*256];    // bf16 xn chunks, XOR-swz (Y A-frags)
    __shared__ unsigned short sx2nB[16*256];   // bf16 x2n chunks (FFN1 A-frags)
    __shared__ unsigned short sH[16*1024];     // h, frag layout (FFN2 A-frags)
    __shared__ float sP[16][17];
    __shared__ float sW1e[3][128];
    __shared__ float sW2e[3][576];
    __shared__ float sSig[560];
    __shared__ float sMask[16];
    __shared__ float sO[6*256];
    __shared__ float sRs[240];
    __shared__ float sRsA[48];
    __shared__ unsigned short sYb[2][16*264];  // Y_blk double buffer
    __shared__ float sX[16][257];              // x2 rows

    const int bb = blockIdx.x, tid = threadIdx.x;
    const int w = tid >> 6, lane = tid & 63;
    const int rr = lane & 15, kq = lane >> 4;

    // ---- A. LayerNorm 1 (32 threads/row, 8 elems each) ----
    {
        int r = tid >> 5, q = tid & 31;
        const float* row = x + ((size_t)bb*16 + r)*256 + q*8;
        float4 va = *(const float4*)row, vb = *(const float4*)(row + 4);
        float v[8] = {va.x, va.y, va.z, va.w, vb.x, vb.y, vb.z, vb.w};
        float sum = 0.f, ss = 0.f;
        #pragma unroll
        for (int m = 0; m < 8; ++m) { sum += v[m]; ss += v[m]*v[m]; }
        #pragma unroll
        for (int o = 16; o; o >>= 1) { sum += __shfl_xor(sum, o); ss += __shfl_xor(ss, o); }
        float mean = sum * (1.f/256.f);
        float rstd = rsqrtf(ss*(1.f/256.f) - mean*mean + LNEPS);
        U4 pk;
        #pragma unroll
        for (int m = 0; m < 8; ++m) {
            int c = q*8 + m;
            float xv = (v[m]-mean)*rstd*n1_g[c] + n1_b[c];
            sxn[r][c] = xv;
            pk.us[m] = f2bf(xv);
        }
        int swz = (q & 24) | ((q & 7) ^ (r & 7));
        *(uint4*)&sxnB[r*256 + swz*8] = pk.u4;
        if (tid < 16) sMask[tid] = mask[bb*16 + tid];
        for (int i = tid; i < 560; i += 512) sSig[i] = sg[i];
    }
    __syncthreads();

    // ---- B. P = xn @ geom_w + geom_b (2 threads per output) ----
    {
        int r = tid >> 5, g = (tid >> 1) & 15, half = tid & 1;
        int cb = half * 128;
        float a0 = 0.f, a1 = 0.f, a2 = 0.f, a3 = 0.f;
        for (int c = 0; c < 128; c += 4) {
            a0 += sxn[r][cb+c+0] * geom_w[(cb+c+0)*16 + g];
            a1 += sxn[r][cb+c+1] * geom_w[(cb+c+1)*16 + g];
            a2 += sxn[r][cb+c+2] * geom_w[(cb+c+2)*16 + g];
            a3 += sxn[r][cb+c+3] * geom_w[(cb+c+3)*16 + g];
        }
        float p = (a0+a1) + (a2+a3);
        p += __shfl_xor(p, 1);
        if (!half) sP[r][g] = p + geom_b[g];
    }
    __syncthreads();

    // ---- C. W1: (e, s) over 480 threads; zero-pad 120..127 ----
    {
        int e = tid >> 2, s = tid & 3;
        if (e < 120 && s < 3) {
            int i0 = e_i[e], j0 = e_j[e];
            float d2 = 0.f;
            #pragma unroll
            for (int m = 0; m < 16; ++m) { float dd = sP[i0][m] - sP[j0][m]; d2 += dd*dd; }
            float mm = sMask[i0]*sMask[j0];
            d2 *= mm*mm;
            float sc = expf(log_sc[s]);
            sW1e[s][e] = expf(-d2/(2.f*sc*sc + 1e-8f)) * mm;
        }
        if (tid < 24) sW1e[tid >> 3][120 + (tid & 7)] = 0.f;
    }
    __syncthreads();

    // ---- D. W2 (3x560) + mask extension ----
    for (int t = tid; t < 560; t += 512) {
        int a = t_ij[t], b2 = t_jk[t], c2 = t_ik[t];
        #pragma unroll
        for (int s = 0; s < 3; ++s) sW2e[s][t] = sW1e[s][a]*sW1e[s][b2]*sW1e[s][c2];
    }
    if (tid < 48) sW2e[tid >> 4][560 + (tid & 15)] = sMask[tid & 15];
    __syncthreads();

    // ---- E. waves 0-2: edge O (MFMA); wave 3: node O; waves 4-7: rsA partials ----
    if (w < 3) {
        int s = w;
        f32x4 acc = {0.f, 0.f, 0.f, 0.f};
        for (int kt = 0; kt < 18; ++kt) {
            U4 ub; ub.u4 = ufrag[kt*64 + lane];
            const float4* w4 = (const float4*)&sW2e[s][kt*32 + kq*8];
            float4 wa = w4[0], wb = w4[1];
            U4 av;
            av.us[0] = f2bf(wa.x * bf2f(ub.us[0]));
            av.us[1] = f2bf(wa.y * bf2f(ub.us[1]));
            av.us[2] = f2bf(wa.z * bf2f(ub.us[2]));
            av.us[3] = f2bf(wa.w * bf2f(ub.us[3]));
            av.us[4] = f2bf(wb.x * bf2f(ub.us[4]));
            av.us[5] = f2bf(wb.y * bf2f(ub.us[5]));
            av.us[6] = f2bf(wb.z * bf2f(ub.us[6]));
            av.us[7] = f2bf(wb.w * bf2f(ub.us[7]));
            acc = __builtin_amdgcn_mfma_f32_16x16x32_bf16(av.bv, ub.bv, acc, 0, 0, 0);
        }
        #pragma unroll
        for (int e = 0; e < 4; ++e) {
            int row = kq*4 + e;
            sO[(3+s)*256 + row*16 + rr] = acc[e] + TAUF*C1[row*16 + rr];
        }
    } else if (w == 3) {
        f32x4 acc3[3];
        acc3[0] = 0.f; acc3[1] = 0.f; acc3[2] = 0.f;
        for (int kt = 0; kt < 4; ++kt) {
            U4 ub; ub.u4 = b1frag[kt*64 + lane];
            float uf[8];
            #pragma unroll
            for (int j = 0; j < 8; ++j) uf[j] = bf2f(ub.us[j]);
            #pragma unroll
            for (int s = 0; s < 3; ++s) {
                const float4* w4 = (const float4*)&sW1e[s][kt*32 + kq*8];
                float4 wa = w4[0], wb = w4[1];
                U4 av;
                av.us[0] = f2bf(wa.x * uf[0]);
                av.us[1] = f2bf(wa.y * uf[1]);
                av.us[2] = f2bf(wa.z * uf[2]);
                av.us[3] = f2bf(wa.w * uf[3]);
                av.us[4] = f2bf(wb.x * uf[4]);
                av.us[5] = f2bf(wb.y * uf[5]);
                av.us[6] = f2bf(wb.z * uf[6]);
                av.us[7] = f2bf(wb.w * uf[7]);
                acc3[s] = __builtin_amdgcn_mfma_f32_16x16x32_bf16(av.bv, ub.bv, acc3[s], 0, 0, 0);
            }
        }
        #pragma unroll
        for (int s = 0; s < 3; ++s)
            #pragma unroll
            for (int e = 0; e < 4; ++e) {
                int row = kq*4 + e;
                sO[s*256 + row*16 + rr] = acc3[s][e] + ((row == rr) ? TAUF : 0.f);
            }
    } else {
        int idx = tid - 256;
        if (idx < 240) {
            int s = idx / 80, rem = idx % 80;
            int k = rem / 5, ch = rem % 5;
            float p = 0.f;
            int t0 = ch * 112;
            for (int i = 0; i < 112; ++i) {
                int t = t0 + i;
                p += sW2e[s][t] * sSig[t] * Up[k*560 + t];
            }
            sRs[(s*16 + k)*5 + ch] = p;
        }
    }
    __syncthreads();

    // ---- F. rsA combine + blk-wise Y-GEMM + O-contraction + epilogue -> sX ----
    if (tid < 48) {
        int k = tid & 15;
        float a = TAUF * r2[k];
        #pragma unroll
        for (int p = 0; p < 16; ++p) a += C0[k*16 + p] * sMask[p] * r1[p];
        #pragma unroll
        for (int ch = 0; ch < 5; ++ch) a += sRs[tid*5 + ch];
        sRsA[tid] = a;
    }
    {
        const int o = tid & 255, kh = tid >> 8;   // kh uniform per wave
        float accX[8] = {0.f,0.f,0.f,0.f,0.f,0.f,0.f,0.f};
        for (int blk = 0; blk < 6; ++blk) {
            // Y tiles: wave w computes n-local [w*32, w*32+32)
            f32x4 ya0 = {0.f,0.f,0.f,0.f}, ya1 = ya0;
            #pragma unroll
            for (int kt = 0; kt < 8; ++kt) {
                int kg = kt*4 + kq;
                int swz = (kg & 24) | ((kg & 7) ^ (rr & 7));
                bf16x8 af = *(const bf16x8*)&sxnB[rr*256 + swz*8];
                U4 b0, b1;
                b0.u4 = *(const uint4*)(Qt + (size_t)(blk*256 + w*32 +      rr)*256 + kt*32 + kq*8);
                b1.u4 = *(const uint4*)(Qt + (size_t)(blk*256 + w*32 + 16 + rr)*256 + kt*32 + kq*8);
                ya0 = __builtin_amdgcn_mfma_f32_16x16x32_bf16(af, b0.bv, ya0, 0, 0, 0);
                ya1 = __builtin_amdgcn_mfma_f32_16x16x32_bf16(af, b1.bv, ya1, 0, 0, 0);
            }
            int buf = blk & 1;
            #pragma unroll
            for (int e = 0; e < 4; ++e) {
                int l = kq*4 + e;
                sYb[buf][l*264 + w*32 +      rr] = f2bf(ya0[e]);
                sYb[buf][l*264 + w*32 + 16 + rr] = f2bf(ya1[e]);
            }
            __syncthreads();
            #pragma unroll
            for (int l = 0; l < 16; ++l) {
                float y = bf2f(sYb[buf][l*264 + o]);
                #pragma unroll
                for (int i = 0; i < 8; ++i)
                    accX[i] += sO[blk*256 + (kh*8 + i)*16 + l] * y;
            }
        }
        float b0v = bias0[o], c0v = ce[o], c1v = ce[256+o], c2v = ce[512+o];
        #pragma unroll
        for (int i = 0; i < 8; ++i) {
            int k = kh*8 + i;
            float v = accX[i] + b0v
                    + sRsA[     k] * c0v
                    + sRsA[16 + k] * c1v
                    + sRsA[32 + k] * c2v
                    + x[((size_t)bb*16 + k)*256 + o];
            sX[k][o] = v;
        }
    }
    __syncthreads();

    // ---- G. LN2 -> sx2nB (bf16 frag chunks) ----
    {
        int r = tid >> 5, q = tid & 31;
        float v[8]; float sum = 0.f, ss = 0.f;
        #pragma unroll
        for (int m = 0; m < 8; ++m) { float t = sX[r][q*8 + m]; v[m] = t; sum += t; ss += t*t; }
        #pragma unroll
        for (int o = 16; o; o >>= 1) { sum += __shfl_xor(sum, o); ss += __shfl_xor(ss, o); }
        float mean = sum * (1.f/256.f);
        float rstd = rsqrtf(ss*(1.f/256.f) - mean*mean + LNEPS);
        U4 pk;
        #pragma unroll
        for (int m = 0; m < 8; ++m) {
            int c = q*8 + m;
            pk.us[m] = f2bf((v[m]-mean)*rstd*n2g[c] + n2b[c]);
        }
        int swz = (q & 24) | ((q & 7) ^ (r & 7));
        *(uint4*)&sx2nB[r*256 + swz*8] = pk.u4;
    }
    __syncthreads();

    // ---- H. FFN1: h = gelu(x2n @ w1t^T + b1) -> sH (frag layout) ----
    #pragma unroll
    for (int j = 0; j < 8; ++j) {
        int nt = w*8 + j;
        f32x4 acc = {0.f,0.f,0.f,0.f};
        #pragma unroll
        for (int kt = 0; kt < 8; ++kt) {
            int kg = kt*4 + kq;
            int swz = (kg & 24) | ((kg & 7) ^ (rr & 7));
            bf16x8 af = *(const bf16x8*)&sx2nB[rr*256 + swz*8];
            U4 bv; bv.u4 = *(const uint4*)(w1t + (size_t)(nt*16 + rr)*256 + kt*32 + kq*8);
            acc = __builtin_amdgcn_mfma_f32_16x16x32_bf16(af, bv.bv, acc, 0, 0, 0);
        }
        int n = nt*16 + rr;
        float bias = f1b[n];
        int hkg = n >> 3, hlo = n & 7;
        #pragma unroll
        for (int e = 0; e < 4; ++e) {
            int m = kq*4 + e;
            float v = acc[e] + bias;
            v = 0.5f * v * (1.f + erff(v * 0.70710678118654752f));
            int hswz = (hkg & 120) | ((hkg & 7) ^ (m & 7));
            sH[m*1024 + hswz*8 + hlo] = f2bf(v);
        }
    }
    __syncthreads();

    // ---- I. FFN2: out = x2 + h @ w2t^T + b2 ----
    #pragma unroll
    for (int j = 0; j < 2; ++j) {
        int nt = w*2 + j;
        f32x4 acc = {0.f,0.f,0.f,0.f};
        for (int kt = 0; kt < 32; ++kt) {
            int hkg = kt*4 + kq;
            int hswz = (hkg & 120) | ((hkg & 7) ^ (rr & 7));
            bf16x8 af = *(const bf16x8*)&sH[rr*1024 + hswz*8];
            U4 bv; bv.u4 = *(const uint4*)(w2t + (size_t)(nt*16 + rr)*1024 + kt*32 + kq*8);
            acc = __builtin_amdgcn_mfma_f32_16x16x32_bf16(af, bv.bv, acc, 0, 0, 0);
        }
        int col = nt*16 + rr;
        float bias = f2b[col];
        #pragma unroll
        for (int e = 0; e < 4; ++e) {
            int row = kq*4 + e;
            outp[((size_t)bb*16 + row)*256 + col] = acc[e] + bias + sX[row][col];
        }
    }
}

extern "C" void kernel_launch(void* const* d_in, const int* in_sizes, int n_in,
                              void* d_out, int out_size, void* d_ws, size_t ws_size,
                              hipStream_t stream)
{
    (void)in_sizes; (void)n_in; (void)out_size;
    const float* x      = (const float*)d_in[0];
    const float* mask   = (const float*)d_in[1];
    const float* B1g    = (const float*)d_in[2];
    const float* B2g    = (const float*)d_in[3];
    const float* absB1  = (const float*)d_in[4];
    const int*   e_i    = (const int*)d_in[5];
    const int*   e_j    = (const int*)d_in[6];
    const int*   t_ij   = (const int*)d_in[7];
    const int*   t_jk   = (const int*)d_in[8];
    const int*   t_ik   = (const int*)d_in[9];
    const float* geom_w = (const float*)d_in[10];
    const float* geom_b = (const float*)d_in[11];
    const float* log_sc = (const float*)d_in[12];
    const float* wv0_w  = (const float*)d_in[13];
    const float* wv0_b  = (const float*)d_in[14];
    const float* wein_w = (const float*)d_in[15];
    const float* wein_b = (const float*)d_in[16];
    const float* out_w  = (const float*)d_in[17];
    const float* out_b  = (const float*)d_in[18];
    const float* n1_g   = (const float*)d_in[19];
    const float* n1_b   = (const float*)d_in[20];
    const float* n2_g   = (const float*)d_in[21];
    const float* n2_b   = (const float*)d_in[22];
    const float* ffn1_w = (const float*)d_in[23];
    const float* ffn1_b = (const float*)d_in[24];
    const float* ffn2_w = (const float*)d_in[25];
    const float* ffn2_b = (const float*)d_in[26];

    float* out = (float*)d_out;
    float* ws  = (float*)d_ws;
    if (ws_size < (size_t)WS_FLOATS * sizeof(float)) return;

    float* ce    = ws + CE_OFF;
    float* bias0 = ws + B0_OFF;
    float* C0    = ws + C0_OFF;
    float* C1    = ws + C1_OFF;
    float* U     = ws + U_OFF;
    float* sg    = ws + SG_OFF;
    float* r1    = ws + R1_OFF;
    float* r2    = ws + R2_OFF;
    uint4* ufrag  = (uint4*)(ws + UF_OFF);
    uint4* b1frag = (uint4*)(ws + B1F_OFF);
    unsigned short* wvb   = (unsigned short*)(ws + WVB_OFF);
    unsigned short* weinb = (unsigned short*)(ws + WEB_OFF);
    unsigned short* owTB  = (unsigned short*)(ws + OWT_OFF);
    unsigned short* Qt  = (unsigned short*)(ws + QT_OFF);
    unsigned short* w1t = (unsigned short*)(ws + W1T_OFF);
    unsigned short* w2t = (unsigned short*)(ws + W2T_OFF);

    wprep_k<<<1150, 256, 0, stream>>>(wv0_w, wein_w, out_w, ffn1_w, ffn2_w,
                                      wv0_b, wein_b, out_b, B1g, absB1, B2g,
                                      wvb, weinb, owTB, w1t, w2t,
                                      ce, bias0, C0, C1, U, sg, r1, r2,
                                      ufrag, b1frag);
    q_mfma_k<<<dim3(4, 24), 256, 0, stream>>>(owTB, wvb, weinb, Qt);
    k_mega<<<256, 512, 0, stream>>>(x, mask, e_i, e_j, t_ij, t_jk, t_ik,
                                    geom_w, geom_b, log_sc, n1_g, n1_b, n2_g, n2_b,
                                    C0, C1, U, sg, r1, r2, ufrag, b1frag,
                                    Qt, bias0, ce,
                                    w1t, ffn1_b, w2t, ffn2_b, out);
}

// Round 6
// 103.486 us; speedup vs baseline: 3.1523x; 1.1629x over previous
//
#include <hip/hip_runtime.h>
#include <math.h>

#define TAUF  1.0e-4f
#define LNEPS 1.0e-5f

typedef __bf16 bf16x8 __attribute__((ext_vector_type(8)));
typedef float  f32x4  __attribute__((ext_vector_type(4)));

union U4 { uint4 u4; unsigned short us[8]; bf16x8 bv; };

static __device__ __forceinline__ unsigned short f2bf(float f) {
    union { float f; unsigned u; } v; v.f = f;
    unsigned r = v.u + 0x7fffu + ((v.u >> 16) & 1u);
    return (unsigned short)(r >> 16);
}
static __device__ __forceinline__ float bf2f(unsigned short h) {
    union { unsigned u; float f; } v; v.u = ((unsigned)h) << 16;
    return v.f;
}

// ---------------- workspace layout (float offsets, all 16B-aligned) ----------------
static const unsigned CE_OFF   = 0u;         // 3*256                  -> 768
static const unsigned B0_OFF   = 768u;       // 256                    -> 1024
static const unsigned C0_OFF   = 1024u;      // 256                    -> 1280
static const unsigned C1_OFF   = 1280u;      // 256                    -> 1536
static const unsigned U_OFF    = 1536u;      // 16*560                 -> 10496
static const unsigned SG_OFF   = 10496u;     // 560                    -> 11056
static const unsigned R1_OFF   = 11056u;     // 16                     -> 11072
static const unsigned R2_OFF   = 11072u;     // 16                     -> 11088
static const unsigned UF_OFF   = 11088u;     // 18*64 uint4 (4608 f)   -> 15696
static const unsigned B1F_OFF  = 15696u;     // 4*64 uint4  (1024 f)   -> 16720
static const unsigned QT_OFF   = 16720u;     // 393216 bf16 (196608 f) -> 213328
static const unsigned W1T_OFF  = 213328u;    // 262144 bf16 (131072 f) -> 344400
static const unsigned W2T_OFF  = 344400u;    // 262144 bf16 (131072 f) -> 475472
static const unsigned WS_FLOATS = 475472u;   // ~1.9 MB

// ================= prep: ALL x-independent prep in ONE launch =================
// b <  96 : Qt MFMA GEMM directly from f32 out_w / wv0_w / wein_w
// b < 352 : transpose ffn1_w -> w1t bf16
// b < 608 : transpose ffn2_w -> w2t bf16
// b < 612 : bias folds (ce, bias0)
// b < 648 : complex constants (C0,C1,r1,r2,sigma,U)
// b < 670 : MFMA operand fragments ufrag(18) / b1frag(4)
__launch_bounds__(256)
__global__ void prep_k(const float* __restrict__ wv0_w, const float* __restrict__ wein_w,
                       const float* __restrict__ out_w,
                       const float* __restrict__ ffn1_w, const float* __restrict__ ffn2_w,
                       const float* __restrict__ wv0_b, const float* __restrict__ wein_b,
                       const float* __restrict__ out_b,
                       const float* __restrict__ B1g, const float* __restrict__ absB1,
                       const float* __restrict__ B2g,
                       unsigned short* __restrict__ Qt,
                       unsigned short* __restrict__ w1t, unsigned short* __restrict__ w2t,
                       float* __restrict__ ce, float* __restrict__ bias0,
                       float* __restrict__ C0, float* __restrict__ C1,
                       float* __restrict__ U, float* __restrict__ sigma,
                       float* __restrict__ r1, float* __restrict__ r2,
                       uint4* __restrict__ ufrag, uint4* __restrict__ b1frag)
{
    __shared__ float tile[32][33];
    __shared__ float sTf[64][65];
    __shared__ unsigned short sAb[64*264];
    int b = blockIdx.x, tid = threadIdx.x;
    if (b < 96) {
        // ---- Qt[row=blk*256+o][c'] = sum_d out_w[blk*256+d][o] * Wsel[c'][s*256+d] ----
        int by = b >> 2, bx = b & 3;
        int row0 = by * 64, col0 = bx * 64;
        int z = row0 >> 8, o0 = row0 & 255;
        int s = (z < 3) ? z : z - 3;
        const float* Wsel = (z < 3) ? wv0_w : wein_w;
        // stage A^T slab: sAb[nl][d] = bf16(out_w[z*256+d][o0+nl]), d=0..255
        for (int dc = 0; dc < 4; ++dc) {
            #pragma unroll
            for (int i = 0; i < 16; ++i) {
                int idx = i*256 + tid, dd = idx >> 6, nl = idx & 63;
                sTf[dd][nl] = out_w[(size_t)(z*256 + dc*64 + dd)*256 + o0 + nl];
            }
            __syncthreads();
            #pragma unroll
            for (int i = 0; i < 16; ++i) {
                int idx = i*256 + tid, nl = idx >> 6, dd = idx & 63;
                sAb[nl*264 + dc*64 + dd] = f2bf(sTf[dd][nl]);
            }
            __syncthreads();
        }
        int lane = tid & 63, w = tid >> 6;
        int rr = lane & 15, kq = lane >> 4;
        f32x4 acc[4];
        #pragma unroll
        for (int cg = 0; cg < 4; ++cg) acc[cg] = 0.f;
        for (int ks = 0; ks < 8; ++ks) {
            bf16x8 af = *(const bf16x8*)&sAb[(w*16 + rr)*264 + ks*32 + kq*8];
            #pragma unroll
            for (int cg = 0; cg < 4; ++cg) {
                const float* bp = Wsel + (size_t)(col0 + cg*16 + rr)*768 + s*256 + ks*32 + kq*8;
                float4 b0 = *(const float4*)bp, b1 = *(const float4*)(bp + 4);
                U4 bv;
                bv.us[0]=f2bf(b0.x); bv.us[1]=f2bf(b0.y); bv.us[2]=f2bf(b0.z); bv.us[3]=f2bf(b0.w);
                bv.us[4]=f2bf(b1.x); bv.us[5]=f2bf(b1.y); bv.us[6]=f2bf(b1.z); bv.us[7]=f2bf(b1.w);
                acc[cg] = __builtin_amdgcn_mfma_f32_16x16x32_bf16(af, bv.bv, acc[cg], 0, 0, 0);
            }
        }
        #pragma unroll
        for (int cg = 0; cg < 4; ++cg)
            #pragma unroll
            for (int e = 0; e < 4; ++e) {
                int row = row0 + w*16 + kq*4 + e;
                int col = col0 + cg*16 + rr;
                Qt[(size_t)row*256 + col] = f2bf(acc[cg][e]);
            }
    } else if (b < 352) {
        int bi = b - 96;                       // ffn1_w [256][1024] -> w1t [1024][256]
        int c0 = (bi & 31) * 32, r0 = (bi >> 5) * 32;
        int tx = tid & 31, ty = tid >> 5;
        #pragma unroll
        for (int i = 0; i < 4; ++i)
            tile[ty + i*8][tx] = ffn1_w[(size_t)(r0 + ty + i*8)*1024 + c0 + tx];
        __syncthreads();
        #pragma unroll
        for (int i = 0; i < 4; ++i)
            w1t[(size_t)(c0 + ty + i*8)*256 + r0 + tx] = f2bf(tile[tx][ty + i*8]);
    } else if (b < 608) {
        int bi = b - 352;                      // ffn2_w [1024][256] -> w2t [256][1024]
        int c0 = (bi & 7) * 32, r0 = (bi >> 3) * 32;
        int tx = tid & 31, ty = tid >> 5;
        #pragma unroll
        for (int i = 0; i < 4; ++i)
            tile[ty + i*8][tx] = ffn2_w[(size_t)(r0 + ty + i*8)*256 + c0 + tx];
        __syncthreads();
        #pragma unroll
        for (int i = 0; i < 4; ++i)
            w2t[(size_t)(c0 + ty + i*8)*1024 + r0 + tx] = f2bf(tile[tx][ty + i*8]);
    } else if (b < 612) {
        int which = b - 608;
        int o = tid;
        if (which == 3) {
            float acc = 0.f;
            for (int r = 0; r < 768; ++r) acc += wv0_b[r] * out_w[(size_t)r*256 + o];
            bias0[o] = out_b[o] + TAUF * acc;
        } else {
            float a2 = 0.f;
            for (int c = 0; c < 256; ++c)
                a2 += wein_b[which*256 + c] * out_w[(size_t)(768 + which*256 + c)*256 + o];
            ce[which*256 + o] = a2;
        }
    } else if (b < 648) {
        int sub = b - 612;
        if (sub == 0) {
            int p = tid >> 4, q = tid & 15;
            float c0 = 0.f, c1 = 0.f;
            for (int e = 0; e < 120; ++e) {
                float ap = absB1[p*120+e];
                c0 += ap * B1g[q*120+e];
                c1 += ap * absB1[q*120+e];
            }
            C0[tid] = c0; C1[tid] = c1;
            if (tid < 16) {
                float a = 0.f, bb = 0.f;
                for (int e = 0; e < 120; ++e) { a += B1g[tid*120+e]; bb += absB1[tid*120+e]; }
                r1[tid] = a; r2[tid] = bb;
            }
            for (int t = tid; t < 560; t += 256) {
                float s2 = 0.f;
                for (int e = 0; e < 120; ++e) s2 += B2g[e*560+t];
                sigma[t] = s2;
            }
        } else {
            int idx = (sub - 1) * 256 + tid;    // 0..8959
            int p = idx / 560, t = idx % 560;
            float u = 0.f;
            for (int e = 0; e < 120; ++e) u += absB1[p*120+e] * B2g[e*560+t];
            U[idx] = u;
        }
    } else {
        if (tid < 64) {
            int lane = tid, col = lane & 15, kq = lane >> 4;
            int fb = b - 648;
            U4 o;
            if (fb < 18) {
                int kt = fb;
                #pragma unroll
                for (int j = 0; j < 8; ++j) {
                    int t = kt*32 + kq*8 + j;
                    float v = 0.f;
                    if (t < 560) {
                        for (int e = 0; e < 120; ++e) v += absB1[col*120+e] * B2g[e*560+t];
                    } else {
                        int p = t - 560;
                        for (int e = 0; e < 120; ++e) v += absB1[col*120+e] * B1g[p*120+e];
                    }
                    o.us[j] = f2bf(v);
                }
                ufrag[kt*64 + lane] = o.u4;
            } else {
                int kt = fb - 18;
                #pragma unroll
                for (int j = 0; j < 8; ++j) {
                    int e = kt*32 + kq*8 + j;
                    o.us[j] = f2bf((e < 120) ? B1g[col*120 + e] : 0.f);
                }
                b1frag[kt*64 + lane] = o.u4;
            }
        }
    }
}

// ============== k_mega: full per-batch pipeline, 1024 threads (16 waves = 4/SIMD) ==============
__launch_bounds__(1024)
__global__ void k_mega(const float* __restrict__ x, const float* __restrict__ mask,
                       const int* __restrict__ e_i, const int* __restrict__ e_j,
                       const int* __restrict__ t_ij, const int* __restrict__ t_jk,
                       const int* __restrict__ t_ik,
                       const float* __restrict__ geom_w, const float* __restrict__ geom_b,
                       const float* __restrict__ log_sc,
                       const float* __restrict__ n1_g, const float* __restrict__ n1_b,
                       const float* __restrict__ n2g, const float* __restrict__ n2b,
                       const float* __restrict__ C0, const float* __restrict__ C1,
                       const float* __restrict__ Up, const float* __restrict__ sg,
                       const float* __restrict__ r1, const float* __restrict__ r2,
                       const uint4* __restrict__ ufrag, const uint4* __restrict__ b1frag,
                       const unsigned short* __restrict__ Qt,
                       const float* __restrict__ bias0, const float* __restrict__ ce,
                       const unsigned short* __restrict__ w1t, const float* __restrict__ f1b,
                       const unsigned short* __restrict__ w2t, const float* __restrict__ f2b,
                       float* __restrict__ outp)
{
    __shared__ float sFbuf[16][264];           // xn (phases A-B), then x2 (F-I)
    __shared__ unsigned short sNB[16*256];     // bf16 xn chunks (A-F), then x2n chunks (G-H)
    __shared__ unsigned short sH[16*1024];     // h, frag layout (FFN2 A-frags)
    __shared__ float sP[16][17];
    __shared__ float sW1e[3][128];
    __shared__ float sW2e[3][576];
    __shared__ float sSig[560];
    __shared__ float sMask[16];
    __shared__ float sO[6*256];
    __shared__ float sRs[240];
    __shared__ float sRsA[48];
    __shared__ unsigned short sYb[16*264];     // Y blk tile (single buffer)

    const int bb = blockIdx.x, tid = threadIdx.x;
    const int w = tid >> 6, lane = tid & 63;
    const int rr = lane & 15, kq = lane >> 4;

    // ---- A. LayerNorm 1: wave w = row w, 64 lanes x 4 elems ----
    {
        const int r = w, q = lane;
        const float* row = x + ((size_t)bb*16 + r)*256 + q*4;
        float4 va = *(const float4*)row;
        float v[4] = {va.x, va.y, va.z, va.w};
        float sum = v[0]+v[1]+v[2]+v[3];
        float ss  = v[0]*v[0]+v[1]*v[1]+v[2]*v[2]+v[3]*v[3];
        #pragma unroll
        for (int o = 32; o; o >>= 1) { sum += __shfl_xor(sum, o); ss += __shfl_xor(ss, o); }
        float mean = sum * (1.f/256.f);
        float rstd = rsqrtf(ss*(1.f/256.f) - mean*mean + LNEPS);
        ushort4 pk;
        float xv0 = (v[0]-mean)*rstd*n1_g[q*4+0] + n1_b[q*4+0];
        float xv1 = (v[1]-mean)*rstd*n1_g[q*4+1] + n1_b[q*4+1];
        float xv2 = (v[2]-mean)*rstd*n1_g[q*4+2] + n1_b[q*4+2];
        float xv3 = (v[3]-mean)*rstd*n1_g[q*4+3] + n1_b[q*4+3];
        sFbuf[r][q*4+0] = xv0; sFbuf[r][q*4+1] = xv1;
        sFbuf[r][q*4+2] = xv2; sFbuf[r][q*4+3] = xv3;
        pk.x = f2bf(xv0); pk.y = f2bf(xv1); pk.z = f2bf(xv2); pk.w = f2bf(xv3);
        int kg = q >> 1;
        int swz = (kg & 24) | ((kg & 7) ^ (r & 7));
        *(ushort4*)&sNB[r*256 + swz*8 + (q & 1)*4] = pk;
        if (tid < 16) sMask[tid] = mask[bb*16 + tid];
        for (int i = tid; i < 560; i += 1024) sSig[i] = sg[i];
    }
    __syncthreads();

    // ---- B. P = xn @ geom_w + geom_b: (r, g, quarter) ----
    {
        const int r = w, g = (lane >> 2) & 15, quarter = lane & 3;
        const int cb = quarter * 64;
        float a0 = 0.f, a1 = 0.f, a2 = 0.f, a3 = 0.f;
        for (int c = 0; c < 64; c += 4) {
            a0 += sFbuf[r][cb+c+0] * geom_w[(cb+c+0)*16 + g];
            a1 += sFbuf[r][cb+c+1] * geom_w[(cb+c+1)*16 + g];
            a2 += sFbuf[r][cb+c+2] * geom_w[(cb+c+2)*16 + g];
            a3 += sFbuf[r][cb+c+3] * geom_w[(cb+c+3)*16 + g];
        }
        float p = (a0+a1) + (a2+a3);
        p += __shfl_xor(p, 1);
        p += __shfl_xor(p, 2);
        if (quarter == 0) sP[r][g] = p + geom_b[g];
    }
    __syncthreads();

    // ---- C. W1: e = tid>>3, s = tid&7 ----
    {
        int e = tid >> 3, s = tid & 7;
        if (e < 120 && s < 3) {
            int i0 = e_i[e], j0 = e_j[e];
            float d2 = 0.f;
            #pragma unroll
            for (int m = 0; m < 16; ++m) { float dd = sP[i0][m] - sP[j0][m]; d2 += dd*dd; }
            float mm = sMask[i0]*sMask[j0];
            d2 *= mm*mm;
            float sc = expf(log_sc[s]);
            sW1e[s][e] = expf(-d2/(2.f*sc*sc + 1e-8f)) * mm;
        }
        if (tid < 24) sW1e[tid >> 3][120 + (tid & 7)] = 0.f;
    }
    __syncthreads();

    // ---- D. W2 + mask extension ----
    if (tid < 560) {
        int t = tid;
        int a = t_ij[t], b2 = t_jk[t], c2 = t_ik[t];
        #pragma unroll
        for (int s = 0; s < 3; ++s) sW2e[s][t] = sW1e[s][a]*sW1e[s][b2]*sW1e[s][c2];
    }
    if (tid < 48) sW2e[tid >> 4][560 + (tid & 15)] = sMask[tid & 15];
    __syncthreads();

    // ---- E. waves 0-2: edge O; wave 3: node O; waves 4-7: rsA partials; 8-15 idle ----
    if (w < 3) {
        int s = w;
        f32x4 acc = {0.f, 0.f, 0.f, 0.f};
        for (int kt = 0; kt < 18; ++kt) {
            U4 ub; ub.u4 = ufrag[kt*64 + lane];
            const float4* w4 = (const float4*)&sW2e[s][kt*32 + kq*8];
            float4 wa = w4[0], wb = w4[1];
            U4 av;
            av.us[0] = f2bf(wa.x * bf2f(ub.us[0]));
            av.us[1] = f2bf(wa.y * bf2f(ub.us[1]));
            av.us[2] = f2bf(wa.z * bf2f(ub.us[2]));
            av.us[3] = f2bf(wa.w * bf2f(ub.us[3]));
            av.us[4] = f2bf(wb.x * bf2f(ub.us[4]));
            av.us[5] = f2bf(wb.y * bf2f(ub.us[5]));
            av.us[6] = f2bf(wb.z * bf2f(ub.us[6]));
            av.us[7] = f2bf(wb.w * bf2f(ub.us[7]));
            acc = __builtin_amdgcn_mfma_f32_16x16x32_bf16(av.bv, ub.bv, acc, 0, 0, 0);
        }
        #pragma unroll
        for (int e = 0; e < 4; ++e) {
            int row = kq*4 + e;
            sO[(3+s)*256 + row*16 + rr] = acc[e] + TAUF*C1[row*16 + rr];
        }
    } else if (w == 3) {
        f32x4 acc3[3];
        acc3[0] = 0.f; acc3[1] = 0.f; acc3[2] = 0.f;
        for (int kt = 0; kt < 4; ++kt) {
            U4 ub; ub.u4 = b1frag[kt*64 + lane];
            float uf[8];
            #pragma unroll
            for (int j = 0; j < 8; ++j) uf[j] = bf2f(ub.us[j]);
            #pragma unroll
            for (int s = 0; s < 3; ++s) {
                const float4* w4 = (const float4*)&sW1e[s][kt*32 + kq*8];
                float4 wa = w4[0], wb = w4[1];
                U4 av;
                av.us[0] = f2bf(wa.x * uf[0]);
                av.us[1] = f2bf(wa.y * uf[1]);
                av.us[2] = f2bf(wa.z * uf[2]);
                av.us[3] = f2bf(wa.w * uf[3]);
                av.us[4] = f2bf(wb.x * uf[4]);
                av.us[5] = f2bf(wb.y * uf[5]);
                av.us[6] = f2bf(wb.z * uf[6]);
                av.us[7] = f2bf(wb.w * uf[7]);
                acc3[s] = __builtin_amdgcn_mfma_f32_16x16x32_bf16(av.bv, ub.bv, acc3[s], 0, 0, 0);
            }
        }
        #pragma unroll
        for (int s = 0; s < 3; ++s)
            #pragma unroll
            for (int e = 0; e < 4; ++e) {
                int row = kq*4 + e;
                sO[s*256 + row*16 + rr] = acc3[s][e] + ((row == rr) ? TAUF : 0.f);
            }
    } else if (w < 8) {
        int idx = tid - 256;
        if (idx < 240) {
            int s = idx / 80, rem = idx % 80;
            int k = rem / 5, ch = rem % 5;
            float p = 0.f;
            int t0 = ch * 112;
            for (int i = 0; i < 112; ++i) {
                int t = t0 + i;
                p += sW2e[s][t] * sSig[t] * Up[k*560 + t];
            }
            sRs[(s*16 + k)*5 + ch] = p;
        }
    }
    __syncthreads();

    if (tid < 48) {
        int k = tid & 15;
        float a = TAUF * r2[k];
        #pragma unroll
        for (int p = 0; p < 16; ++p) a += C0[k*16 + p] * sMask[p] * r1[p];
        #pragma unroll
        for (int ch = 0; ch < 5; ++ch) a += sRs[tid*5 + ch];
        sRsA[tid] = a;
    }

    // ---- F. blk-wise Y-GEMM (wave w -> 16 cols) + O-contraction; Qt frags reg-prefetched ----
    {
        const int o = tid & 255, kh = tid >> 8;    // kh: 4 row-quads
        float accX[4] = {0.f, 0.f, 0.f, 0.f};
        U4 qf[8];
        #pragma unroll
        for (int kt = 0; kt < 8; ++kt)
            qf[kt].u4 = *(const uint4*)(Qt + ((size_t)(0*256 + w*16 + rr))*256 + kt*32 + kq*8);
        for (int blk = 0; blk < 6; ++blk) {
            f32x4 ya = {0.f, 0.f, 0.f, 0.f};
            #pragma unroll
            for (int kt = 0; kt < 8; ++kt) {
                int kg = kt*4 + kq;
                int swz = (kg & 24) | ((kg & 7) ^ (rr & 7));
                bf16x8 af = *(const bf16x8*)&sNB[rr*256 + swz*8];
                ya = __builtin_amdgcn_mfma_f32_16x16x32_bf16(af, qf[kt].bv, ya, 0, 0, 0);
            }
            if (blk < 5) {
                #pragma unroll
                for (int kt = 0; kt < 8; ++kt)
                    qf[kt].u4 = *(const uint4*)(Qt + ((size_t)((blk+1)*256 + w*16 + rr))*256 + kt*32 + kq*8);
            }
            __syncthreads();                       // prev contraction done reading sYb
            #pragma unroll
            for (int e = 0; e < 4; ++e) {
                int l = kq*4 + e;
                sYb[l*264 + w*16 + rr] = f2bf(ya[e]);
            }
            __syncthreads();
            #pragma unroll
            for (int l = 0; l < 16; ++l) {
                float y = bf2f(sYb[l*264 + o]);
                #pragma unroll
                for (int i = 0; i < 4; ++i)
                    accX[i] += sO[blk*256 + (kh*4 + i)*16 + l] * y;
            }
        }
        __syncthreads();
        float b0v = bias0[o], c0v = ce[o], c1v = ce[256+o], c2v = ce[512+o];
        #pragma unroll
        for (int i = 0; i < 4; ++i) {
            int k = kh*4 + i;
            float v = accX[i] + b0v
                    + sRsA[     k] * c0v
                    + sRsA[16 + k] * c1v
                    + sRsA[32 + k] * c2v
                    + x[((size_t)bb*16 + k)*256 + o];
            sFbuf[k][o] = v;                       // x2 (sxn is dead)
        }
    }
    __syncthreads();

    // ---- G. LN2 -> sNB (x2n bf16 chunks; sxnB is dead) ----
    {
        const int r = w, q = lane;
        float v[4];
        v[0] = sFbuf[r][q*4+0]; v[1] = sFbuf[r][q*4+1];
        v[2] = sFbuf[r][q*4+2]; v[3] = sFbuf[r][q*4+3];
        float sum = v[0]+v[1]+v[2]+v[3];
        float ss  = v[0]*v[0]+v[1]*v[1]+v[2]*v[2]+v[3]*v[3];
        #pragma unroll
        for (int o = 32; o; o >>= 1) { sum += __shfl_xor(sum, o); ss += __shfl_xor(ss, o); }
        float mean = sum * (1.f/256.f);
        float rstd = rsqrtf(ss*(1.f/256.f) - mean*mean + LNEPS);
        ushort4 pk;
        pk.x = f2bf((v[0]-mean)*rstd*n2g[q*4+0] + n2b[q*4+0]);
        pk.y = f2bf((v[1]-mean)*rstd*n2g[q*4+1] + n2b[q*4+1]);
        pk.z = f2bf((v[2]-mean)*rstd*n2g[q*4+2] + n2b[q*4+2]);
        pk.w = f2bf((v[3]-mean)*rstd*n2g[q*4+3] + n2b[q*4+3]);
        int kg = q >> 1;
        int swz = (kg & 24) | ((kg & 7) ^ (r & 7));
        *(ushort4*)&sNB[r*256 + swz*8 + (q & 1)*4] = pk;
    }
    __syncthreads();

    // ---- H. FFN1: wave w -> 4 n-tiles; h -> sH (frag layout) ----
    {
        U4 wb[8];
        #pragma unroll
        for (int kt = 0; kt < 8; ++kt)
            wb[kt].u4 = *(const uint4*)(w1t + (size_t)((w*4+0)*16 + rr)*256 + kt*32 + kq*8);
        #pragma unroll
        for (int j = 0; j < 4; ++j) {
            int nt = w*4 + j;
            f32x4 acc = {0.f, 0.f, 0.f, 0.f};
            #pragma unroll
            for (int kt = 0; kt < 8; ++kt) {
                int kg = kt*4 + kq;
                int swz = (kg & 24) | ((kg & 7) ^ (rr & 7));
                bf16x8 af = *(const bf16x8*)&sNB[rr*256 + swz*8];
                acc = __builtin_amdgcn_mfma_f32_16x16x32_bf16(af, wb[kt].bv, acc, 0, 0, 0);
            }
            if (j < 3) {
                #pragma unroll
                for (int kt = 0; kt < 8; ++kt)
                    wb[kt].u4 = *(const uint4*)(w1t + (size_t)((nt+1)*16 + rr)*256 + kt*32 + kq*8);
            }
            int n = nt*16 + rr;
            float bias = f1b[n];
            int hkg = n >> 3, hlo = n & 7;
            #pragma unroll
            for (int e = 0; e < 4; ++e) {
                int m = kq*4 + e;
                float v = acc[e] + bias;
                v = 0.5f * v * (1.f + erff(v * 0.70710678118654752f));
                int hswz = (hkg & 120) | ((hkg & 7) ^ (m & 7));
                sH[m*1024 + hswz*8 + hlo] = f2bf(v);
            }
        }
    }
    __syncthreads();

    // ---- I. FFN2: wave w -> 1 n-tile; out = x2 + h @ w2t^T + b2 ----
    {
        U4 qb[8];
        #pragma unroll
        for (int kt = 0; kt < 8; ++kt)
            qb[kt].u4 = *(const uint4*)(w2t + (size_t)(w*16 + rr)*1024 + kt*32 + kq*8);
        f32x4 acc = {0.f, 0.f, 0.f, 0.f};
        #pragma unroll
        for (int grp = 0; grp < 4; ++grp) {
            #pragma unroll
            for (int kt = 0; kt < 8; ++kt) {
                int hkg = (grp*8 + kt)*4 + kq;
                int hswz = (hkg & 120) | ((hkg & 7) ^ (rr & 7));
                bf16x8 af = *(const bf16x8*)&sH[rr*1024 + hswz*8];
                acc = __builtin_amdgcn_mfma_f32_16x16x32_bf16(af, qb[kt].bv, acc, 0, 0, 0);
            }
            if (grp < 3) {
                #pragma unroll
                for (int kt = 0; kt < 8; ++kt)
                    qb[kt].u4 = *(const uint4*)(w2t + (size_t)(w*16 + rr)*1024 + ((grp+1)*8 + kt)*32 + kq*8);
            }
        }
        int col = w*16 + rr;
        float bias = f2b[col];
        #pragma unroll
        for (int e = 0; e < 4; ++e) {
            int row = kq*4 + e;
            outp[((size_t)bb*16 + row)*256 + col] = acc[e] + bias + sFbuf[row][col];
        }
    }
}

extern "C" void kernel_launch(void* const* d_in, const int* in_sizes, int n_in,
                              void* d_out, int out_size, void* d_ws, size_t ws_size,
                              hipStream_t stream)
{
    (void)in_sizes; (void)n_in; (void)out_size;
    const float* x      = (const float*)d_in[0];
    const float* mask   = (const float*)d_in[1];
    const float* B1g    = (const float*)d_in[2];
    const float* B2g    = (const float*)d_in[3];
    const float* absB1  = (const float*)d_in[4];
    const int*   e_i    = (const int*)d_in[5];
    const int*   e_j    = (const int*)d_in[6];
    const int*   t_ij   = (const int*)d_in[7];
    const int*   t_jk   = (const int*)d_in[8];
    const int*   t_ik   = (const int*)d_in[9];
    const float* geom_w = (const float*)d_in[10];
    const float* geom_b = (const float*)d_in[11];
    const float* log_sc = (const float*)d_in[12];
    const float* wv0_w  = (const float*)d_in[13];
    const float* wv0_b  = (const float*)d_in[14];
    const float* wein_w = (const float*)d_in[15];
    const float* wein_b = (const float*)d_in[16];
    const float* out_w  = (const float*)d_in[17];
    const float* out_b  = (const float*)d_in[18];
    const float* n1_g   = (const float*)d_in[19];
    const float* n1_b   = (const float*)d_in[20];
    const float* n2_g   = (const float*)d_in[21];
    const float* n2_b   = (const float*)d_in[22];
    const float* ffn1_w = (const float*)d_in[23];
    const float* ffn1_b = (const float*)d_in[24];
    const float* ffn2_w = (const float*)d_in[25];
    const float* ffn2_b = (const float*)d_in[26];

    float* out = (float*)d_out;
    float* ws  = (float*)d_ws;
    if (ws_size < (size_t)WS_FLOATS * sizeof(float)) return;

    float* ce    = ws + CE_OFF;
    float* bias0 = ws + B0_OFF;
    float* C0    = ws + C0_OFF;
    float* C1    = ws + C1_OFF;
    float* U     = ws + U_OFF;
    float* sg    = ws + SG_OFF;
    float* r1    = ws + R1_OFF;
    float* r2    = ws + R2_OFF;
    uint4* ufrag  = (uint4*)(ws + UF_OFF);
    uint4* b1frag = (uint4*)(ws + B1F_OFF);
    unsigned short* Qt  = (unsigned short*)(ws + QT_OFF);
    unsigned short* w1t = (unsigned short*)(ws + W1T_OFF);
    unsigned short* w2t = (unsigned short*)(ws + W2T_OFF);

    prep_k<<<670, 256, 0, stream>>>(wv0_w, wein_w, out_w, ffn1_w, ffn2_w,
                                    wv0_b, wein_b, out_b, B1g, absB1, B2g,
                                    Qt, w1t, w2t,
                                    ce, bias0, C0, C1, U, sg, r1, r2,
                                    ufrag, b1frag);
    k_mega<<<256, 1024, 0, stream>>>(x, mask, e_i, e_j, t_ij, t_jk, t_ik,
                                     geom_w, geom_b, log_sc, n1_g, n1_b, n2_g, n2_b,
                                     C0, C1, U, sg, r1, r2, ufrag, b1frag,
                                     Qt, bias0, ce,
                                     w1t, ffn1_b, w2t, ffn2_b, out);
}